// Round 9
// baseline (298.976 us; speedup 1.0000x reference)
//
#include <hip/hip_runtime.h>
#include <hip/hip_bf16.h>

typedef unsigned short u16;
typedef unsigned int u32;
using short8 = __attribute__((ext_vector_type(8))) short;
using f32x4  = __attribute__((ext_vector_type(4))) float;

#define T_   64
#define D_   300
#define H_   256
#define G_   768            // 3H
#define NROW 512            // useful sequences (s==2)
#define M_   (NROW * T_)    // 32768
#define KP_  320            // K=300 padded to 320 for MFMA

__device__ __forceinline__ float bf2f(u16 v) {
    union { u32 u; float f; } x; x.u = ((u32)v) << 16; return x.f;
}
__device__ __forceinline__ float bf2f_lo(u32 w) {
    union { u32 u; float f; } x; x.u = w << 16; return x.f;
}
__device__ __forceinline__ float bf2f_hi(u32 w) {
    union { u32 u; float f; } x; x.u = w & 0xFFFF0000u; return x.f;
}
__device__ __forceinline__ u16 f2bf(float f) {
    union { u32 u; float f; } x; x.f = f;
    u32 u = x.u;
    u32 r = (u + 0x7FFFu + ((u >> 16) & 1u)) >> 16;   // RNE
    return (u16)r;
}
__device__ __forceinline__ float frcp(float x) {
    float r; asm("v_rcp_f32 %0, %1" : "=v"(r) : "v"(x)); return r;
}
__device__ __forceinline__ float fsigm(float x) { return frcp(1.f + __expf(-x)); }
__device__ __forceinline__ float ftanh(float x) {
    return 1.f - 2.f * frcp(1.f + __expf(2.f * x));
}
__device__ __forceinline__ float sigm(float x) { return 1.f / (1.f + expf(-x)); }

// ---------------------------------------------------------------------------
// KX: cast x[:,2] (f32) -> xb [32768][320] bf16, zero-padded k>=300.
// ---------------------------------------------------------------------------
__global__ __launch_bounds__(256) void kx_cast(
    const float* __restrict__ x, u16* __restrict__ xb)
{
    const int gid = blockIdx.x * 256 + threadIdx.x;   // 32768*40 threads
    const int row = gid / 40, seg = gid - row * 40;
    const int k0 = seg * 8;
    const int n = row >> 6, t = row & 63;
    const float* src = x + (size_t)(n * 256 + 128 + t) * D_;
    union { u16 h[8]; uint4 q; } u;
    if (k0 + 8 <= D_) {
        const float4 a = *reinterpret_cast<const float4*>(src + k0);
        const float4 b = *reinterpret_cast<const float4*>(src + k0 + 4);
        u.h[0] = f2bf(a.x); u.h[1] = f2bf(a.y); u.h[2] = f2bf(a.z); u.h[3] = f2bf(a.w);
        u.h[4] = f2bf(b.x); u.h[5] = f2bf(b.y); u.h[6] = f2bf(b.z); u.h[7] = f2bf(b.w);
    } else {
#pragma unroll
        for (int e = 0; e < 8; ++e)
            u.h[e] = (k0 + e < D_) ? f2bf(src[k0 + e]) : (u16)0;
    }
    *reinterpret_cast<uint4*>(&xb[(size_t)row * KP_ + k0]) = u.q;
}

// ---------------------------------------------------------------------------
// K0: weight prep + combined bias (b_ih1 + b_hh1 for r,z; b_ih1 for n).
// ---------------------------------------------------------------------------
__global__ __launch_bounds__(256) void k0_prep(
    const float* __restrict__ w_ih1, const float* __restrict__ w_hh1,
    const float* __restrict__ b_ih1, const float* __restrict__ b_hh1,
    const float* __restrict__ w2f, const float* __restrict__ w2b,
    const float* __restrict__ wc1,
    u16* __restrict__ wihb, u16* __restrict__ whpk,
    u16* __restrict__ w2ft, u16* __restrict__ w2bt, u16* __restrict__ wc1t,
    float* __restrict__ biasc)
{
    int y = blockIdx.y;
    int tid = blockIdx.x * 256 + threadIdx.x;
    if (y == 0) {
        if (tid < G_ * KP_) {
            int g = tid / KP_, k = tid % KP_;
            wihb[tid] = (k < D_) ? f2bf(w_ih1[g * D_ + k]) : (u16)0;
        }
    } else if (y == 1) {
        if (tid < 48 * 8 * 64) {
            int lane = tid & 63;
            int ks = (tid >> 6) & 7;
            int nt = tid >> 9;
            int g  = nt * 16 + (lane & 15);
            int kb = ks * 32 + ((lane >> 4) << 3);
            union { u16 h[8]; uint4 q; } u;
#pragma unroll
            for (int e = 0; e < 8; ++e) u.h[e] = f2bf(w_hh1[g * H_ + kb + e]);
            *reinterpret_cast<uint4*>(&whpk[(size_t)tid * 8]) = u.q;
        }
    } else if (y == 2 || y == 3) {
        if (tid < G_ * H_) {
            int k = tid / G_, g = tid % G_;
            const float* src = (y == 2) ? w2f : w2b;
            u16* dst = (y == 2) ? w2ft : w2bt;
            dst[tid] = f2bf(src[g * H_ + k]);
        }
    } else {
        if (tid < 512 * 256) {
            int k = tid / 256, o = tid % 256;
            wc1t[tid] = f2bf(wc1[o * 512 + k]);
        }
        if (tid < G_)
            biasc[tid] = b_ih1[tid] + (tid < 2 * H_ ? b_hh1[tid] : 0.f);
    }
}

// ---------------------------------------------------------------------------
// K1 v2: xgw = (xb @ wihb^T + biasc), bf16 MFMA, 128x128 tile, BK=64,
// double-buffered LDS + async-stage split (loads issued before MFMA,
// ds_write after) -> ONE barrier per k-iter (5 iters).
// Output layout [t][n][3 gates][128 words] u32 (pair unit u, u+16).
// ---------------------------------------------------------------------------
__global__ __launch_bounds__(256, 2) void k1_xgemm(
    const u16* __restrict__ xb, const u16* __restrict__ wihb,
    const float* __restrict__ biasc, u32* __restrict__ xgw)
{
    __shared__ alignas(16) u16 As[2][128][72];   // 36,864 B
    __shared__ alignas(16) u16 Bs[2][128][72];   // 36,864 B
    const int tid = threadIdx.x;
    const int l = tid & 63, wv = tid >> 6;
    const int wrow = wv >> 1, wcol = wv & 1;
    const int row0 = blockIdx.x * 128, col0 = blockIdx.y * 128;
    const int ar = tid >> 1, ah = tid & 1;       // row, k-half (32 u16)

    f32x4 acc[4][4];
#pragma unroll
    for (int i = 0; i < 4; ++i)
#pragma unroll
        for (int j = 0; j < 4; ++j) acc[i][j] = (f32x4){0.f, 0.f, 0.f, 0.f};

    const u16* xrow  = xb + (size_t)(row0 + ar) * KP_ + ah * 32;
    const u16* wrowp = wihb + (size_t)(col0 + ar) * KP_ + ah * 32;

    uint4 ra[4], rb[4];
    auto loadregs = [&](int it) {
        const int k0 = it * 64;
#pragma unroll
        for (int e = 0; e < 4; ++e) {
            ra[e] = *reinterpret_cast<const uint4*>(xrow + k0 + e * 8);
            rb[e] = *reinterpret_cast<const uint4*>(wrowp + k0 + e * 8);
        }
    };
    auto writelds = [&](int buf) {
#pragma unroll
        for (int e = 0; e < 4; ++e) {
            *reinterpret_cast<uint4*>(&As[buf][ar][ah * 32 + e * 8]) = ra[e];
            *reinterpret_cast<uint4*>(&Bs[buf][ar][ah * 32 + e * 8]) = rb[e];
        }
    };

    loadregs(0);
    writelds(0);
    __syncthreads();

    for (int it = 0; it < 5; ++it) {
        const int cur = it & 1;
        if (it < 4) loadregs(it + 1);     // issue early; hidden under MFMA
#pragma unroll
        for (int kc = 0; kc < 2; ++kc) {
            short8 af[4], bf[4];
#pragma unroll
            for (int fi = 0; fi < 4; ++fi)
                af[fi] = *reinterpret_cast<const short8*>(
                    &As[cur][wrow * 64 + fi * 16 + (l & 15)][kc * 32 + ((l >> 4) << 3)]);
#pragma unroll
            for (int fj = 0; fj < 4; ++fj)
                bf[fj] = *reinterpret_cast<const short8*>(
                    &Bs[cur][wcol * 64 + fj * 16 + (l & 15)][kc * 32 + ((l >> 4) << 3)]);
#pragma unroll
            for (int fi = 0; fi < 4; ++fi)
#pragma unroll
                for (int fj = 0; fj < 4; ++fj)
                    acc[fi][fj] = __builtin_amdgcn_mfma_f32_16x16x32_bf16(
                        af[fi], bf[fj], acc[fi][fj], 0, 0, 0);
        }
        if (it < 4) writelds(cur ^ 1);    // write-late into the other buffer
        __syncthreads();
    }

    float bias[4];
#pragma unroll
    for (int fj = 0; fj < 4; ++fj)
        bias[fj] = biasc[col0 + wcol * 64 + fj * 16 + (l & 15)];
#pragma unroll
    for (int fi = 0; fi < 4; ++fi)
#pragma unroll
        for (int fjp = 0; fjp < 2; ++fjp) {
            const int cg0 = col0 + wcol * 64 + fjp * 32;     // a=0,c=0 col
            const int g = cg0 >> 8;
            const int wv8 = (cg0 & 255) >> 5;
            const int word = g * 128 + wv8 * 16 + (l & 15);
#pragma unroll
            for (int q = 0; q < 4; ++q) {
                const int row = row0 + wrow * 64 + fi * 16 + ((l >> 4) << 2) + q;
                const int t = row & 63, n = row >> 6;
                const u32 lo = f2bf(acc[fi][2 * fjp][q] + bias[2 * fjp]);
                const u32 hi = f2bf(acc[fi][2 * fjp + 1][q] + bias[2 * fjp + 1]);
                xgw[((size_t)t * NROW + n) * 384 + word] = lo | (hi << 16);
            }
        }
}

// ---------------------------------------------------------------------------
// K2 v7: 64 blocks x 8 rows, 512 thr. Weights ks0-5 AGPR-pinned, ks6-7 LDS.
// NO shfl redistribution (shuffles are LDS ops on CDNA -> fed the LDS-pipe
// bottleneck): lanes 0-31 hold all valid C rows and do the update for BOTH
// unit halves (half-exec trans cost == full-wave redistributed cost).
// xg prefetched one step ahead. One barrier/step.
// ---------------------------------------------------------------------------
__global__ __launch_bounds__(512)
__attribute__((amdgpu_waves_per_eu(2, 2)))
void k2_gru(const u32* __restrict__ xgw, const u16* __restrict__ whpk,
            const float* __restrict__ b_hh, float* __restrict__ mid)
{
    extern __shared__ u16 smem[];
    u16* wl = smem;                        // ks6-7: 48*2*64*8 u16 = 98304 B
    u16* hb = smem + 48 * 2 * 64 * 8;      // ping-pong 2 x 16*264 u16
    const int tid = threadIdx.x;
    const int l = tid & 63, wv = tid >> 6;   // wv in [0,8)
    const int n0 = blockIdx.x * 8;
    const int c = l & 15, rgrp = l >> 4;
    const int arow = c, klo = rgrp << 3;
    const int rbase = (rgrp & 1) * 4;        // valid for lanes < 32
    const int u0 = wv * 32 + c;              // unit (a=0); a=1 is u0+16

    // weights ks 0..5 (36 x short8 = 144 regs), pinned to AGPRs
    short8 wr[6][6];
#pragma unroll
    for (int gt = 0; gt < 3; ++gt)
#pragma unroll
        for (int a = 0; a < 2; ++a) {
            const int nt = gt * 16 + wv * 2 + a;
#pragma unroll
            for (int ks = 0; ks < 6; ++ks)
                wr[gt * 2 + a][ks] = *reinterpret_cast<const short8*>(
                    &whpk[(size_t)((nt * 8 + ks) * 64 + l) * 8]);
        }
    asm volatile("" :
        "+a"(wr[0][0]),"+a"(wr[0][1]),"+a"(wr[0][2]),"+a"(wr[0][3]),"+a"(wr[0][4]),"+a"(wr[0][5]),
        "+a"(wr[1][0]),"+a"(wr[1][1]),"+a"(wr[1][2]),"+a"(wr[1][3]),"+a"(wr[1][4]),"+a"(wr[1][5]),
        "+a"(wr[2][0]),"+a"(wr[2][1]),"+a"(wr[2][2]),"+a"(wr[2][3]),"+a"(wr[2][4]),"+a"(wr[2][5]));
    asm volatile("" :
        "+a"(wr[3][0]),"+a"(wr[3][1]),"+a"(wr[3][2]),"+a"(wr[3][3]),"+a"(wr[3][4]),"+a"(wr[3][5]),
        "+a"(wr[4][0]),"+a"(wr[4][1]),"+a"(wr[4][2]),"+a"(wr[4][3]),"+a"(wr[4][4]),"+a"(wr[4][5]),
        "+a"(wr[5][0]),"+a"(wr[5][1]),"+a"(wr[5][2]),"+a"(wr[5][3]),"+a"(wr[5][4]),"+a"(wr[5][5]));

    // stage ks 6..7 into LDS
    for (int cc = tid; cc < 48 * 2 * 64; cc += 512) {
        const int nt = cc >> 7, j = (cc >> 6) & 1, ll = cc & 63;
        *reinterpret_cast<uint4*>(&wl[(size_t)cc * 8]) =
            *reinterpret_cast<const uint4*>(
                &whpk[(size_t)((nt * 8 + 6 + j) * 64 + ll) * 8]);
    }
    for (int i = tid; i < 2 * 16 * 264 / 2; i += 512) ((u32*)hb)[i] = 0;

    const float bhn0 = b_hh[512 + u0];
    const float bhn1 = b_hh[512 + u0 + 16];
    u32 xo[4];
#pragma unroll
    for (int q = 0; q < 4; ++q)
        xo[q] = (u32)(n0 + rbase + q) * 384 + wv * 16 + c;
    float h0[4] = {0.f, 0.f, 0.f, 0.f};
    float h1[4] = {0.f, 0.f, 0.f, 0.f};
    const u32 stepw = (u32)NROW * 384;

    // prologue: load t=0 gates (lanes 0-31 only)
    u32 xa[3][4], xn2[3][4];
    if (l < 32) {
#pragma unroll
        for (int q = 0; q < 4; ++q) {
            xa[0][q] = xgw[xo[q]];
            xa[1][q] = xgw[xo[q] + 128];
            xa[2][q] = xgw[xo[q] + 256];
        }
    }

    __syncthreads();

    int p = 0;
    for (int t = 0; t < T_; ++t) {
        // prefetch next step's gates (hidden under this step)
        if (l < 32) {
            const u32 tb = (u32)(t + 1 < T_ ? t + 1 : T_ - 1) * stepw;
#pragma unroll
            for (int q = 0; q < 4; ++q) {
                xn2[0][q] = xgw[tb + xo[q]];
                xn2[1][q] = xgw[tb + xo[q] + 128];
                xn2[2][q] = xgw[tb + xo[q] + 256];
            }
        }

        // MFMA phase: read hb[p] (all lanes)
        const u16* hbr = hb + p * (16 * 264);
        f32x4 acc[6];
#pragma unroll
        for (int m = 0; m < 6; ++m) acc[m] = (f32x4){0.f, 0.f, 0.f, 0.f};
        __builtin_amdgcn_s_setprio(1);
#pragma unroll
        for (int ks = 0; ks < 6; ++ks) {
            const short8 afr = *reinterpret_cast<const short8*>(
                &hbr[arow * 264 + ks * 32 + klo]);
#pragma unroll
            for (int m = 0; m < 6; ++m)
                acc[m] = __builtin_amdgcn_mfma_f32_16x16x32_bf16(
                    afr, wr[m][ks], acc[m], 0, 0, 0);
        }
#pragma unroll
        for (int ks = 6; ks < 8; ++ks) {
            const short8 afr = *reinterpret_cast<const short8*>(
                &hbr[arow * 264 + ks * 32 + klo]);
#pragma unroll
            for (int gt = 0; gt < 3; ++gt)
#pragma unroll
                for (int a = 0; a < 2; ++a) {
                    const int nt2 = (gt * 16 + wv * 2 + a) * 2 + (ks - 6);
                    const short8 bfr = *reinterpret_cast<const short8*>(
                        &wl[(size_t)(nt2 * 64 + l) * 8]);
                    acc[gt * 2 + a] = __builtin_amdgcn_mfma_f32_16x16x32_bf16(
                        afr, bfr, acc[gt * 2 + a], 0, 0, 0);
                }
        }
        __builtin_amdgcn_s_setprio(0);

        // update phase: lanes 0-31 hold valid rows 0-7; each does both halves
        u16* hbw = hb + (p ^ 1) * (16 * 264);
        if (l < 32) {
#pragma unroll
            for (int q = 0; q < 4; ++q) {
                const float rg0 = fsigm(bf2f_lo(xa[0][q]) + acc[0][q]);
                const float zg0 = fsigm(bf2f_lo(xa[1][q]) + acc[2][q]);
                const float ng0 = ftanh(bf2f_lo(xa[2][q]) + rg0 * (acc[4][q] + bhn0));
                h0[q] = zg0 * (h0[q] - ng0) + ng0;
                hbw[(rbase + q) * 264 + u0] = f2bf(h0[q]);

                const float rg1 = fsigm(bf2f_hi(xa[0][q]) + acc[1][q]);
                const float zg1 = fsigm(bf2f_hi(xa[1][q]) + acc[3][q]);
                const float ng1 = ftanh(bf2f_hi(xa[2][q]) + rg1 * (acc[5][q] + bhn1));
                h1[q] = zg1 * (h1[q] - ng1) + ng1;
                hbw[(rbase + q) * 264 + u0 + 16] = f2bf(h1[q]);
            }
            // roll prefetch regs
#pragma unroll
            for (int g = 0; g < 3; ++g)
#pragma unroll
                for (int q = 0; q < 4; ++q) xa[g][q] = xn2[g][q];
        }

        // single barrier per step
        asm volatile("s_waitcnt lgkmcnt(0)" ::: "memory");
        __builtin_amdgcn_sched_barrier(0);
        __builtin_amdgcn_s_barrier();
        __builtin_amdgcn_sched_barrier(0);
        p ^= 1;
    }

    if (l < 32) {
#pragma unroll
        for (int q = 0; q < 4; ++q) {
            mid[(size_t)(n0 + rbase + q) * H_ + u0] = h0[q];
            mid[(size_t)(n0 + rbase + q) * H_ + u0 + 16] = h1[q];
        }
    }
}

// ---------------------------------------------------------------------------
// K3: head. (unchanged)
// ---------------------------------------------------------------------------
__global__ __launch_bounds__(256) void k3_head(
    const float* __restrict__ mid,
    const u16* __restrict__ w2ft, const u16* __restrict__ w2bt,
    const float* __restrict__ b_ih2f, const float* __restrict__ b_hh2f,
    const float* __restrict__ b_ih2b, const float* __restrict__ b_hh2b,
    const u16* __restrict__ wc1t, const float* __restrict__ bc1,
    const float* __restrict__ wc2, const float* __restrict__ bc2,
    float* __restrict__ out)
{
    __shared__ float m[4][H_];
    __shared__ float xg2[2][4][G_];
    __shared__ float emb[4][512];
    __shared__ float hid[4][H_];
    int tid = threadIdx.x;
    int r0 = blockIdx.x * 4;

    for (int i = tid; i < 4 * H_; i += 256) {
        int r = i >> 8, k = i & 255;
        m[r][k] = mid[(size_t)(r0 + r) * H_ + k];
    }
    __syncthreads();

    const int g0 = tid, g1 = tid + 256, g2 = tid + 512;
    float bf0 = b_ih2f[g0] + b_hh2f[g0];
    float bf1 = b_ih2f[g1] + b_hh2f[g1];
    float bf2v = b_ih2f[g2];
    float bb0 = b_ih2b[g0] + b_hh2b[g0];
    float bb1 = b_ih2b[g1] + b_hh2b[g1];
    float bb2v = b_ih2b[g2];
    float af[4][3], ab[4][3];
#pragma unroll
    for (int r = 0; r < 4; ++r) {
        af[r][0] = bf0; af[r][1] = bf1; af[r][2] = bf2v;
        ab[r][0] = bb0; ab[r][1] = bb1; ab[r][2] = bb2v;
    }
#pragma unroll 4
    for (int k = 0; k < H_; ++k) {
        float wf0 = bf2f(w2ft[k * G_ + g0]);
        float wf1 = bf2f(w2ft[k * G_ + g1]);
        float wf2 = bf2f(w2ft[k * G_ + g2]);
        float wb0 = bf2f(w2bt[k * G_ + g0]);
        float wb1 = bf2f(w2bt[k * G_ + g1]);
        float wb2 = bf2f(w2bt[k * G_ + g2]);
#pragma unroll
        for (int r = 0; r < 4; ++r) {
            float mm = m[r][k];
            af[r][0] += mm * wf0; af[r][1] += mm * wf1; af[r][2] += mm * wf2;
            ab[r][0] += mm * wb0; ab[r][1] += mm * wb1; ab[r][2] += mm * wb2;
        }
    }
#pragma unroll
    for (int r = 0; r < 4; ++r) {
        xg2[0][r][g0] = af[r][0]; xg2[0][r][g1] = af[r][1]; xg2[0][r][g2] = af[r][2];
        xg2[1][r][g0] = ab[r][0]; xg2[1][r][g1] = ab[r][1]; xg2[1][r][g2] = ab[r][2];
    }
    __syncthreads();

    {
        const int j = tid;
        float bnf = b_hh2f[512 + j], bnb = b_hh2b[512 + j];
#pragma unroll
        for (int r = 0; r < 4; ++r) {
            float rg = sigm(xg2[0][r][j]);
            float zg = sigm(xg2[0][r][256 + j]);
            float ng = tanhf(xg2[0][r][512 + j] + rg * bnf);
            emb[r][j] = (1.f - zg) * ng;
            rg = sigm(xg2[1][r][j]);
            zg = sigm(xg2[1][r][256 + j]);
            ng = tanhf(xg2[1][r][512 + j] + rg * bnb);
            emb[r][256 + j] = (1.f - zg) * ng;
        }
    }
    __syncthreads();

    {
        const int o = tid;
        float acc[4];
        float b = bc1[o];
#pragma unroll
        for (int r = 0; r < 4; ++r) acc[r] = b;
#pragma unroll 4
        for (int k = 0; k < 512; ++k) {
            float w = bf2f(wc1t[k * H_ + o]);
#pragma unroll
            for (int r = 0; r < 4; ++r) acc[r] += emb[r][k] * w;
        }
#pragma unroll
        for (int r = 0; r < 4; ++r) {
            float pre = acc[r];
            hid[r][o] = pre >= 0.f ? pre : 0.1f * pre;
        }
    }
    __syncthreads();

    {
        int grp = tid >> 5, lane = tid & 31;
        int r = grp >> 1, cc = grp & 1;
        float s = 0.f;
        for (int k = lane; k < H_; k += 32) s += hid[r][k] * wc2[cc * H_ + k];
#pragma unroll
        for (int msk = 16; msk >= 1; msk >>= 1) s += __shfl_xor(s, msk, 32);
        if (lane == 0) out[(size_t)(r0 + r) * 2 + cc] = s + bc2[cc];
    }
}

// ---------------------------------------------------------------------------
extern "C" void kernel_launch(void* const* d_in, const int* in_sizes, int n_in,
                              void* d_out, int out_size, void* d_ws, size_t ws_size,
                              hipStream_t stream)
{
    const float* x      = (const float*)d_in[0];
    const float* w_ih1  = (const float*)d_in[1];
    const float* w_hh1  = (const float*)d_in[2];
    const float* b_ih1  = (const float*)d_in[3];
    const float* b_hh1  = (const float*)d_in[4];
    const float* w_ih2f = (const float*)d_in[5];
    const float* b_ih2f = (const float*)d_in[7];
    const float* b_hh2f = (const float*)d_in[8];
    const float* w_ih2b = (const float*)d_in[9];
    const float* b_ih2b = (const float*)d_in[11];
    const float* b_hh2b = (const float*)d_in[12];
    const float* wc1    = (const float*)d_in[13];
    const float* bc1    = (const float*)d_in[14];
    const float* wc2    = (const float*)d_in[15];
    const float* bc2    = (const float*)d_in[16];
    float* out = (float*)d_out;

    char* p = (char*)d_ws;
    u32* xgw  = (u32*)p;  p += (size_t)M_ * 384 * 4;         // 48 MB [t][n][3][128]u32
    u16* xb   = (u16*)p;  p += (size_t)M_ * KP_ * 2;         // 20 MB
    u16* wihb = (u16*)p;  p += (size_t)G_ * KP_ * 2;         // 480 KB
    u16* whpk = (u16*)p;  p += (size_t)48 * 8 * 64 * 8 * 2;  // 384 KB
    u16* w2ft = (u16*)p;  p += (size_t)G_ * H_ * 2;
    u16* w2bt = (u16*)p;  p += (size_t)G_ * H_ * 2;
    u16* wc1t = (u16*)p;  p += (size_t)512 * 256 * 2;
    float* mid = (float*)p; p += (size_t)NROW * H_ * 4;
    float* biasc = (float*)p; p += (size_t)G_ * 4;

    kx_cast<<<M_ * 40 / 256, 256, 0, stream>>>(x, xb);
    k0_prep<<<dim3(960, 5), 256, 0, stream>>>(w_ih1, w_hh1, b_ih1, b_hh1,
                                              w_ih2f, w_ih2b, wc1,
                                              wihb, whpk, w2ft, w2bt, wc1t, biasc);
    k1_xgemm<<<dim3(M_ / 128, G_ / 128), 256, 0, stream>>>(xb, wihb, biasc, xgw);
    const int k2_lds = (48 * 2 * 64 * 8 + 2 * 16 * 264) * 2;   // 115200 B
    k2_gru<<<64, 512, k2_lds, stream>>>(xgw, whpk, b_hh1, mid);
    k3_head<<<128, 256, 0, stream>>>(mid, w2ft, w2bt, b_ih2f, b_hh2f,
                                     b_ih2b, b_hh2b, wc1t, bc1, wc2, bc2, out);
}

// Round 12
// 268.640 us; speedup vs baseline: 1.1129x; 1.1129x over previous
//
#include <hip/hip_runtime.h>
#include <hip/hip_bf16.h>

typedef unsigned short u16;
typedef unsigned int u32;
using short8 = __attribute__((ext_vector_type(8))) short;
using f32x4  = __attribute__((ext_vector_type(4))) float;

#define T_   64
#define D_   300
#define H_   256
#define G_   768            // 3H
#define NROW 512            // useful sequences (s==2)
#define M_   (NROW * T_)    // 32768
#define KP_  320            // K=300 padded to 320 for MFMA

__device__ __forceinline__ float bf2f(u16 v) {
    union { u32 u; float f; } x; x.u = ((u32)v) << 16; return x.f;
}
__device__ __forceinline__ u16 f2bf(float f) {
    union { u32 u; float f; } x; x.f = f;
    u32 u = x.u;
    u32 r = (u + 0x7FFFu + ((u >> 16) & 1u)) >> 16;   // RNE
    return (u16)r;
}
__device__ __forceinline__ float frcp(float x) {
    float r; asm("v_rcp_f32 %0, %1" : "=v"(r) : "v"(x)); return r;
}
__device__ __forceinline__ float fsigm(float x) { return frcp(1.f + __expf(-x)); }
__device__ __forceinline__ float ftanh(float x) {
    return 1.f - 2.f * frcp(1.f + __expf(2.f * x));
}
__device__ __forceinline__ float sigm(float x) { return 1.f / (1.f + expf(-x)); }

// ---------------------------------------------------------------------------
// KX: cast x[:,2] (f32) -> xb [32768][320] bf16, zero-padded k>=300.
// ---------------------------------------------------------------------------
__global__ __launch_bounds__(256) void kx_cast(
    const float* __restrict__ x, u16* __restrict__ xb)
{
    const int gid = blockIdx.x * 256 + threadIdx.x;   // 32768*40 threads
    const int row = gid / 40, seg = gid - row * 40;
    const int k0 = seg * 8;
    const int n = row >> 6, t = row & 63;
    const float* src = x + (size_t)(n * 256 + 128 + t) * D_;
    union { u16 h[8]; uint4 q; } u;
    if (k0 + 8 <= D_) {
        const float4 a = *reinterpret_cast<const float4*>(src + k0);
        const float4 b = *reinterpret_cast<const float4*>(src + k0 + 4);
        u.h[0] = f2bf(a.x); u.h[1] = f2bf(a.y); u.h[2] = f2bf(a.z); u.h[3] = f2bf(a.w);
        u.h[4] = f2bf(b.x); u.h[5] = f2bf(b.y); u.h[6] = f2bf(b.z); u.h[7] = f2bf(b.w);
    } else {
#pragma unroll
        for (int e = 0; e < 8; ++e)
            u.h[e] = (k0 + e < D_) ? f2bf(src[k0 + e]) : (u16)0;
    }
    *reinterpret_cast<uint4*>(&xb[(size_t)row * KP_ + k0]) = u.q;
}

// ---------------------------------------------------------------------------
// K0: weight prep + combined bias (b_ih1 + b_hh1 for r,z; b_ih1 for n).
// ---------------------------------------------------------------------------
__global__ __launch_bounds__(256) void k0_prep(
    const float* __restrict__ w_ih1, const float* __restrict__ w_hh1,
    const float* __restrict__ b_ih1, const float* __restrict__ b_hh1,
    const float* __restrict__ w2f, const float* __restrict__ w2b,
    const float* __restrict__ wc1,
    u16* __restrict__ wihb, u16* __restrict__ whpk,
    u16* __restrict__ w2ft, u16* __restrict__ w2bt, u16* __restrict__ wc1t,
    float* __restrict__ biasc)
{
    int y = blockIdx.y;
    int tid = blockIdx.x * 256 + threadIdx.x;
    if (y == 0) {
        if (tid < G_ * KP_) {
            int g = tid / KP_, k = tid % KP_;
            wihb[tid] = (k < D_) ? f2bf(w_ih1[g * D_ + k]) : (u16)0;
        }
    } else if (y == 1) {
        if (tid < 48 * 8 * 64) {
            int lane = tid & 63;
            int ks = (tid >> 6) & 7;
            int nt = tid >> 9;
            int g  = nt * 16 + (lane & 15);
            int kb = ks * 32 + ((lane >> 4) << 3);
            union { u16 h[8]; uint4 q; } u;
#pragma unroll
            for (int e = 0; e < 8; ++e) u.h[e] = f2bf(w_hh1[g * H_ + kb + e]);
            *reinterpret_cast<uint4*>(&whpk[(size_t)tid * 8]) = u.q;
        }
    } else if (y == 2 || y == 3) {
        if (tid < G_ * H_) {
            int k = tid / G_, g = tid % G_;
            const float* src = (y == 2) ? w2f : w2b;
            u16* dst = (y == 2) ? w2ft : w2bt;
            dst[tid] = f2bf(src[g * H_ + k]);
        }
    } else {
        if (tid < 512 * 256) {
            int k = tid / 256, o = tid % 256;
            wc1t[tid] = f2bf(wc1[o * 512 + k]);
        }
        if (tid < G_)
            biasc[tid] = b_ih1[tid] + (tid < 2 * H_ ? b_hh1[tid] : 0.f);
    }
}

// ---------------------------------------------------------------------------
// K1 (round-8 version): xgw = (xb @ wihb^T + biasc), bf16 MFMA, 128x128 tile.
// Output [t][n][3 gates][128 words] u32; word g*128+wv8*16+c packs the bf16
// pair (unit wv8*32+c, unit wv8*32+16+c). Coalesced u32 stores.
// ---------------------------------------------------------------------------
__global__ __launch_bounds__(256) void k1_xgemm(
    const u16* __restrict__ xb, const u16* __restrict__ wihb,
    const float* __restrict__ biasc, u32* __restrict__ xgw)
{
    __shared__ alignas(16) u16 As[128 * 40];
    __shared__ alignas(16) u16 Bs[128 * 40];
    const int tid = threadIdx.x;
    const int l = tid & 63, wv = tid >> 6;
    const int wrow = wv >> 1, wcol = wv & 1;
    const int row0 = blockIdx.x * 128, col0 = blockIdx.y * 128;

    f32x4 acc[4][4];
#pragma unroll
    for (int i = 0; i < 4; ++i)
#pragma unroll
        for (int j = 0; j < 4; ++j) acc[i][j] = (f32x4){0.f, 0.f, 0.f, 0.f};

    const int ar = tid >> 1, ah = tid & 1;
    const u16* xrow  = xb + (size_t)(row0 + ar) * KP_;
    const u16* wrowp = wihb + (size_t)(col0 + ar) * KP_;

    for (int k0 = 0; k0 < KP_; k0 += 32) {
        *reinterpret_cast<uint4*>(&As[ar * 40 + ah * 16]) =
            *reinterpret_cast<const uint4*>(xrow + k0 + ah * 16);
        *reinterpret_cast<uint4*>(&As[ar * 40 + ah * 16 + 8]) =
            *reinterpret_cast<const uint4*>(xrow + k0 + ah * 16 + 8);
        *reinterpret_cast<uint4*>(&Bs[ar * 40 + ah * 16]) =
            *reinterpret_cast<const uint4*>(wrowp + k0 + ah * 16);
        *reinterpret_cast<uint4*>(&Bs[ar * 40 + ah * 16 + 8]) =
            *reinterpret_cast<const uint4*>(wrowp + k0 + ah * 16 + 8);
        __syncthreads();

        short8 af[4], bf[4];
#pragma unroll
        for (int fi = 0; fi < 4; ++fi)
            af[fi] = *reinterpret_cast<const short8*>(
                &As[(wrow * 64 + fi * 16 + (l & 15)) * 40 + ((l >> 4) << 3)]);
#pragma unroll
        for (int fj = 0; fj < 4; ++fj)
            bf[fj] = *reinterpret_cast<const short8*>(
                &Bs[(wcol * 64 + fj * 16 + (l & 15)) * 40 + ((l >> 4) << 3)]);
#pragma unroll
        for (int fi = 0; fi < 4; ++fi)
#pragma unroll
            for (int fj = 0; fj < 4; ++fj)
                acc[fi][fj] = __builtin_amdgcn_mfma_f32_16x16x32_bf16(
                    af[fi], bf[fj], acc[fi][fj], 0, 0, 0);
        __syncthreads();
    }

    float bias[4];
#pragma unroll
    for (int fj = 0; fj < 4; ++fj)
        bias[fj] = biasc[col0 + wcol * 64 + fj * 16 + (l & 15)];
#pragma unroll
    for (int fi = 0; fi < 4; ++fi)
#pragma unroll
        for (int fjp = 0; fjp < 2; ++fjp) {
            const int cg0 = col0 + wcol * 64 + fjp * 32;     // a=0,c=0 col
            const int g = cg0 >> 8;
            const int wv8 = (cg0 & 255) >> 5;
            const int word = g * 128 + wv8 * 16 + (l & 15);
#pragma unroll
            for (int q = 0; q < 4; ++q) {
                const int row = row0 + wrow * 64 + fi * 16 + ((l >> 4) << 2) + q;
                const int t = row & 63, n = row >> 6;
                const u32 lo = f2bf(acc[fi][2 * fjp][q] + bias[2 * fjp]);
                const u32 hi = f2bf(acc[fi][2 * fjp + 1][q] + bias[2 * fjp + 1]);
                xgw[((size_t)t * NROW + n) * 384 + word] = lo | (hi << 16);
            }
        }
}

// ---------------------------------------------------------------------------
// K2 v9: 32 blocks x 16 rows, 256 thr (4 waves, 1/EU). NO cross-lane
// redistribution: with 16 valid rows, every MFMA C row is valid, and the
// (r,z,n) triplet for (row=(l>>4)*4+q, unit=64wv+16j+c) sits in ONE lane
// (acc[j], acc[4+j], acc[8+j]). Weights: 64 frags AGPR-pinned (r,z) + 32
// frags VGPR-pinned (n) = all 96 on-chip; zero LDS weight reads.
// ---------------------------------------------------------------------------
__global__ __launch_bounds__(256)
__attribute__((amdgpu_waves_per_eu(1, 1)))
void k2_gru(const u32* __restrict__ xgw, const u16* __restrict__ whpk,
            const float* __restrict__ b_hh, float* __restrict__ mid)
{
    __shared__ u16 hb[2][16 * 264];        // ping-pong, 16,896 B
    const int tid = threadIdx.x;
    const int l = tid & 63, wv = tid >> 6;   // wv in [0,4)
    const int n0 = blockIdx.x * 16;
    const int c = l & 15, rgrp = l >> 4;
    const int arow = c, klo = rgrp << 3;

    // wave owns units [64wv, 64wv+64): tile m = g*4+j, nt = g*16 + 4wv + j.
    // AGPR: m 0..7 (gates r,z).  VGPR: m 8..11 (gate n).
    short8 wa[8][8];
#pragma unroll
    for (int m = 0; m < 8; ++m) {
        const int nt = (m >> 2) * 16 + 4 * wv + (m & 3);
#pragma unroll
        for (int ks = 0; ks < 8; ++ks)
            wa[m][ks] = *reinterpret_cast<const short8*>(
                &whpk[(size_t)((nt * 8 + ks) * 64 + l) * 8]);
    }
    short8 wn[4][8];
#pragma unroll
    for (int m = 0; m < 4; ++m) {
        const int nt = 32 + 4 * wv + m;
#pragma unroll
        for (int ks = 0; ks < 8; ++ks)
            wn[m][ks] = *reinterpret_cast<const short8*>(
                &whpk[(size_t)((nt * 8 + ks) * 64 + l) * 8]);
    }
    // one-time pins: asm-defined => rematerialization illegal.
    asm volatile("" :
        "+a"(wa[0][0]),"+a"(wa[0][1]),"+a"(wa[0][2]),"+a"(wa[0][3]),
        "+a"(wa[0][4]),"+a"(wa[0][5]),"+a"(wa[0][6]),"+a"(wa[0][7]),
        "+a"(wa[1][0]),"+a"(wa[1][1]),"+a"(wa[1][2]),"+a"(wa[1][3]),
        "+a"(wa[1][4]),"+a"(wa[1][5]),"+a"(wa[1][6]),"+a"(wa[1][7]));
    asm volatile("" :
        "+a"(wa[2][0]),"+a"(wa[2][1]),"+a"(wa[2][2]),"+a"(wa[2][3]),
        "+a"(wa[2][4]),"+a"(wa[2][5]),"+a"(wa[2][6]),"+a"(wa[2][7]),
        "+a"(wa[3][0]),"+a"(wa[3][1]),"+a"(wa[3][2]),"+a"(wa[3][3]),
        "+a"(wa[3][4]),"+a"(wa[3][5]),"+a"(wa[3][6]),"+a"(wa[3][7]));
    asm volatile("" :
        "+a"(wa[4][0]),"+a"(wa[4][1]),"+a"(wa[4][2]),"+a"(wa[4][3]),
        "+a"(wa[4][4]),"+a"(wa[4][5]),"+a"(wa[4][6]),"+a"(wa[4][7]),
        "+a"(wa[5][0]),"+a"(wa[5][1]),"+a"(wa[5][2]),"+a"(wa[5][3]),
        "+a"(wa[5][4]),"+a"(wa[5][5]),"+a"(wa[5][6]),"+a"(wa[5][7]));
    asm volatile("" :
        "+a"(wa[6][0]),"+a"(wa[6][1]),"+a"(wa[6][2]),"+a"(wa[6][3]),
        "+a"(wa[6][4]),"+a"(wa[6][5]),"+a"(wa[6][6]),"+a"(wa[6][7]),
        "+a"(wa[7][0]),"+a"(wa[7][1]),"+a"(wa[7][2]),"+a"(wa[7][3]),
        "+a"(wa[7][4]),"+a"(wa[7][5]),"+a"(wa[7][6]),"+a"(wa[7][7]));
    asm volatile("" :
        "+v"(wn[0][0]),"+v"(wn[0][1]),"+v"(wn[0][2]),"+v"(wn[0][3]),
        "+v"(wn[0][4]),"+v"(wn[0][5]),"+v"(wn[0][6]),"+v"(wn[0][7]),
        "+v"(wn[1][0]),"+v"(wn[1][1]),"+v"(wn[1][2]),"+v"(wn[1][3]),
        "+v"(wn[1][4]),"+v"(wn[1][5]),"+v"(wn[1][6]),"+v"(wn[1][7]));
    asm volatile("" :
        "+v"(wn[2][0]),"+v"(wn[2][1]),"+v"(wn[2][2]),"+v"(wn[2][3]),
        "+v"(wn[2][4]),"+v"(wn[2][5]),"+v"(wn[2][6]),"+v"(wn[2][7]),
        "+v"(wn[3][0]),"+v"(wn[3][1]),"+v"(wn[3][2]),"+v"(wn[3][3]),
        "+v"(wn[3][4]),"+v"(wn[3][5]),"+v"(wn[3][6]),"+v"(wn[3][7]));

    for (int i = tid; i < 2 * 16 * 264 / 2; i += 256)
        reinterpret_cast<u32*>(hb)[i] = 0;

    float bhn[4];
#pragma unroll
    for (int j = 0; j < 4; ++j)
        bhn[j] = b_hh[512 + 64 * wv + 16 * j + c];
    u32 xo[4];
#pragma unroll
    for (int q = 0; q < 4; ++q)
        xo[q] = (u32)(n0 + rgrp * 4 + q) * 384 + c;
    float h[4][4] = {};
    const u32 stepw = (u32)NROW * 384;

    // prologue: load t=0 gates (24 u32/lane: 3 gates x 2 j-pairs x 4 rows)
    u32 xw[3][2][4];
#pragma unroll
    for (int q = 0; q < 4; ++q)
#pragma unroll
        for (int g = 0; g < 3; ++g)
#pragma unroll
            for (int pp = 0; pp < 2; ++pp)
                xw[g][pp][q] = xgw[xo[q] + g * 128 + (2 * wv + pp) * 16];

    __syncthreads();

    int p = 0;
    for (int t = 0; t < T_; ++t) {
        // ---- MFMA phase: hg = h @ W (12 tiles), weights all in regs ----
        const u16* hbr = hb[p];
        f32x4 acc[12];
#pragma unroll
        for (int m = 0; m < 12; ++m) acc[m] = (f32x4){0.f, 0.f, 0.f, 0.f};
        __builtin_amdgcn_s_setprio(1);
#pragma unroll
        for (int ks = 0; ks < 8; ++ks) {
            const short8 afr = *reinterpret_cast<const short8*>(
                &hbr[arow * 264 + ks * 32 + klo]);
#pragma unroll
            for (int m = 0; m < 8; ++m)
                acc[m] = __builtin_amdgcn_mfma_f32_16x16x32_bf16(
                    afr, wa[m][ks], acc[m], 0, 0, 0);
#pragma unroll
            for (int m = 0; m < 4; ++m)
                acc[8 + m] = __builtin_amdgcn_mfma_f32_16x16x32_bf16(
                    afr, wn[m][ks], acc[8 + m], 0, 0, 0);
        }
        __builtin_amdgcn_s_setprio(0);

        // ---- update: 16 gate-triplets per lane, all in-lane (no shuffles).
        //      unit u(j) = 64wv + 16j + c; row = rgrp*4 + q.
        //      xw word pp=j>>1 packs (j even -> lo16, j odd -> hi16). ----
        u16* hbw = hb[p ^ 1];
#pragma unroll
        for (int j = 0; j < 4; ++j) {
            const int pw = j >> 1, shv = (j & 1) << 4;
#pragma unroll
            for (int q = 0; q < 4; ++q) {
                const float xr = bf2f((u16)(xw[0][pw][q] >> shv));
                const float xz = bf2f((u16)(xw[1][pw][q] >> shv));
                const float xn = bf2f((u16)(xw[2][pw][q] >> shv));
                const float rg = fsigm(xr + acc[j][q]);
                const float zg = fsigm(xz + acc[4 + j][q]);
                const float ng = ftanh(xn + rg * (acc[8 + j][q] + bhn[j]));
                h[j][q] = zg * (h[j][q] - ng) + ng;
                hbw[(rgrp * 4 + q) * 264 + 64 * wv + 16 * j + c] = f2bf(h[j][q]);
            }
        }

        // ---- issue next step's gate loads (cover: barrier + MFMA phase) ----
        const u32 tb = (u32)(t + 1 < T_ ? t + 1 : T_ - 1) * stepw;
#pragma unroll
        for (int q = 0; q < 4; ++q)
#pragma unroll
            for (int g = 0; g < 3; ++g)
#pragma unroll
                for (int pp = 0; pp < 2; ++pp)
                    xw[g][pp][q] = xgw[tb + xo[q] + g * 128 + (2 * wv + pp) * 16];

        // single barrier per step (lgkm only; vmcnt stays in flight)
        asm volatile("s_waitcnt lgkmcnt(0)" ::: "memory");
        __builtin_amdgcn_sched_barrier(0);
        __builtin_amdgcn_s_barrier();
        __builtin_amdgcn_sched_barrier(0);
        p ^= 1;
    }

#pragma unroll
    for (int j = 0; j < 4; ++j)
#pragma unroll
        for (int q = 0; q < 4; ++q)
            mid[(size_t)(n0 + rgrp * 4 + q) * H_ + 64 * wv + 16 * j + c] = h[j][q];
}

// ---------------------------------------------------------------------------
// K3: head. (unchanged)
// ---------------------------------------------------------------------------
__global__ __launch_bounds__(256) void k3_head(
    const float* __restrict__ mid,
    const u16* __restrict__ w2ft, const u16* __restrict__ w2bt,
    const float* __restrict__ b_ih2f, const float* __restrict__ b_hh2f,
    const float* __restrict__ b_ih2b, const float* __restrict__ b_hh2b,
    const u16* __restrict__ wc1t, const float* __restrict__ bc1,
    const float* __restrict__ wc2, const float* __restrict__ bc2,
    float* __restrict__ out)
{
    __shared__ float m[4][H_];
    __shared__ float xg2[2][4][G_];
    __shared__ float emb[4][512];
    __shared__ float hid[4][H_];
    int tid = threadIdx.x;
    int r0 = blockIdx.x * 4;

    for (int i = tid; i < 4 * H_; i += 256) {
        int r = i >> 8, k = i & 255;
        m[r][k] = mid[(size_t)(r0 + r) * H_ + k];
    }
    __syncthreads();

    const int g0 = tid, g1 = tid + 256, g2 = tid + 512;
    float bf0 = b_ih2f[g0] + b_hh2f[g0];
    float bf1 = b_ih2f[g1] + b_hh2f[g1];
    float bf2v = b_ih2f[g2];
    float bb0 = b_ih2b[g0] + b_hh2b[g0];
    float bb1 = b_ih2b[g1] + b_hh2b[g1];
    float bb2v = b_ih2b[g2];
    float af[4][3], ab[4][3];
#pragma unroll
    for (int r = 0; r < 4; ++r) {
        af[r][0] = bf0; af[r][1] = bf1; af[r][2] = bf2v;
        ab[r][0] = bb0; ab[r][1] = bb1; ab[r][2] = bb2v;
    }
#pragma unroll 4
    for (int k = 0; k < H_; ++k) {
        float wf0 = bf2f(w2ft[k * G_ + g0]);
        float wf1 = bf2f(w2ft[k * G_ + g1]);
        float wf2 = bf2f(w2ft[k * G_ + g2]);
        float wb0 = bf2f(w2bt[k * G_ + g0]);
        float wb1 = bf2f(w2bt[k * G_ + g1]);
        float wb2 = bf2f(w2bt[k * G_ + g2]);
#pragma unroll
        for (int r = 0; r < 4; ++r) {
            float mm = m[r][k];
            af[r][0] += mm * wf0; af[r][1] += mm * wf1; af[r][2] += mm * wf2;
            ab[r][0] += mm * wb0; ab[r][1] += mm * wb1; ab[r][2] += mm * wb2;
        }
    }
#pragma unroll
    for (int r = 0; r < 4; ++r) {
        xg2[0][r][g0] = af[r][0]; xg2[0][r][g1] = af[r][1]; xg2[0][r][g2] = af[r][2];
        xg2[1][r][g0] = ab[r][0]; xg2[1][r][g1] = ab[r][1]; xg2[1][r][g2] = ab[r][2];
    }
    __syncthreads();

    {
        const int j = tid;
        float bnf = b_hh2f[512 + j], bnb = b_hh2b[512 + j];
#pragma unroll
        for (int r = 0; r < 4; ++r) {
            float rg = sigm(xg2[0][r][j]);
            float zg = sigm(xg2[0][r][256 + j]);
            float ng = tanhf(xg2[0][r][512 + j] + rg * bnf);
            emb[r][j] = (1.f - zg) * ng;
            rg = sigm(xg2[1][r][j]);
            zg = sigm(xg2[1][r][256 + j]);
            ng = tanhf(xg2[1][r][512 + j] + rg * bnb);
            emb[r][256 + j] = (1.f - zg) * ng;
        }
    }
    __syncthreads();

    {
        const int o = tid;
        float acc[4];
        float b = bc1[o];
#pragma unroll
        for (int r = 0; r < 4; ++r) acc[r] = b;
#pragma unroll 4
        for (int k = 0; k < 512; ++k) {
            float w = bf2f(wc1t[k * H_ + o]);
#pragma unroll
            for (int r = 0; r < 4; ++r) acc[r] += emb[r][k] * w;
        }
#pragma unroll
        for (int r = 0; r < 4; ++r) {
            float pre = acc[r];
            hid[r][o] = pre >= 0.f ? pre : 0.1f * pre;
        }
    }
    __syncthreads();

    {
        int grp = tid >> 5, lane = tid & 31;
        int r = grp >> 1, cc = grp & 1;
        float s = 0.f;
        for (int k = lane; k < H_; k += 32) s += hid[r][k] * wc2[cc * H_ + k];
#pragma unroll
        for (int msk = 16; msk >= 1; msk >>= 1) s += __shfl_xor(s, msk, 32);
        if (lane == 0) out[(size_t)(r0 + r) * 2 + cc] = s + bc2[cc];
    }
}

// ---------------------------------------------------------------------------
extern "C" void kernel_launch(void* const* d_in, const int* in_sizes, int n_in,
                              void* d_out, int out_size, void* d_ws, size_t ws_size,
                              hipStream_t stream)
{
    const float* x      = (const float*)d_in[0];
    const float* w_ih1  = (const float*)d_in[1];
    const float* w_hh1  = (const float*)d_in[2];
    const float* b_ih1  = (const float*)d_in[3];
    const float* b_hh1  = (const float*)d_in[4];
    const float* w_ih2f = (const float*)d_in[5];
    const float* b_ih2f = (const float*)d_in[7];
    const float* b_hh2f = (const float*)d_in[8];
    const float* w_ih2b = (const float*)d_in[9];
    const float* b_ih2b = (const float*)d_in[11];
    const float* b_hh2b = (const float*)d_in[12];
    const float* wc1    = (const float*)d_in[13];
    const float* bc1    = (const float*)d_in[14];
    const float* wc2    = (const float*)d_in[15];
    const float* bc2    = (const float*)d_in[16];
    float* out = (float*)d_out;

    char* p = (char*)d_ws;
    u32* xgw  = (u32*)p;  p += (size_t)M_ * 384 * 4;         // 48 MB [t][n][3][128]u32
    u16* xb   = (u16*)p;  p += (size_t)M_ * KP_ * 2;         // 20 MB
    u16* wihb = (u16*)p;  p += (size_t)G_ * KP_ * 2;         // 480 KB
    u16* whpk = (u16*)p;  p += (size_t)48 * 8 * 64 * 8 * 2;  // 384 KB
    u16* w2ft = (u16*)p;  p += (size_t)G_ * H_ * 2;
    u16* w2bt = (u16*)p;  p += (size_t)G_ * H_ * 2;
    u16* wc1t = (u16*)p;  p += (size_t)512 * 256 * 2;
    float* mid = (float*)p; p += (size_t)NROW * H_ * 4;
    float* biasc = (float*)p; p += (size_t)G_ * 4;

    kx_cast<<<M_ * 40 / 256, 256, 0, stream>>>(x, xb);
    k0_prep<<<dim3(960, 5), 256, 0, stream>>>(w_ih1, w_hh1, b_ih1, b_hh1,
                                              w_ih2f, w_ih2b, wc1,
                                              wihb, whpk, w2ft, w2bt, wc1t, biasc);
    k1_xgemm<<<dim3(M_ / 128, G_ / 128), 256, 0, stream>>>(xb, wihb, biasc, xgw);
    k2_gru<<<32, 256, 0, stream>>>(xgw, whpk, b_hh1, mid);
    k3_head<<<128, 256, 0, stream>>>(mid, w2ft, w2bt, b_ih2f, b_hh2f,
                                     b_ih2b, b_hh2b, wc1t, bc1, wc2, bc2, out);
}

// Round 13
// 267.149 us; speedup vs baseline: 1.1191x; 1.0056x over previous
//
#include <hip/hip_runtime.h>
#include <hip/hip_bf16.h>

typedef unsigned short u16;
typedef unsigned int u32;
using short8 = __attribute__((ext_vector_type(8))) short;
using f32x4  = __attribute__((ext_vector_type(4))) float;

#define T_   64
#define D_   300
#define H_   256
#define G_   768            // 3H
#define NROW 512            // useful sequences (s==2)
#define M_   (NROW * T_)    // 32768
#define KP_  320            // K=300 padded to 320 for MFMA

__device__ __forceinline__ float bf2f(u16 v) {
    union { u32 u; float f; } x; x.u = ((u32)v) << 16; return x.f;
}
__device__ __forceinline__ u16 f2bf(float f) {
    union { u32 u; float f; } x; x.f = f;
    u32 u = x.u;
    u32 r = (u + 0x7FFFu + ((u >> 16) & 1u)) >> 16;   // RNE
    return (u16)r;
}
__device__ __forceinline__ float frcp(float x) {
    float r; asm("v_rcp_f32 %0, %1" : "=v"(r) : "v"(x)); return r;
}
__device__ __forceinline__ float fsigm(float x) { return frcp(1.f + __expf(-x)); }
__device__ __forceinline__ float ftanh(float x) {
    return 1.f - 2.f * frcp(1.f + __expf(2.f * x));
}
__device__ __forceinline__ float sigm(float x) { return 1.f / (1.f + expf(-x)); }

// ---------------------------------------------------------------------------
// KX: cast x[:,2] (f32) -> xb [32768][320] bf16, zero-padded k>=300.
// ---------------------------------------------------------------------------
__global__ __launch_bounds__(256) void kx_cast(
    const float* __restrict__ x, u16* __restrict__ xb)
{
    const int gid = blockIdx.x * 256 + threadIdx.x;   // 32768*40 threads
    const int row = gid / 40, seg = gid - row * 40;
    const int k0 = seg * 8;
    const int n = row >> 6, t = row & 63;
    const float* src = x + (size_t)(n * 256 + 128 + t) * D_;
    union { u16 h[8]; uint4 q; } u;
    if (k0 + 8 <= D_) {
        const float4 a = *reinterpret_cast<const float4*>(src + k0);
        const float4 b = *reinterpret_cast<const float4*>(src + k0 + 4);
        u.h[0] = f2bf(a.x); u.h[1] = f2bf(a.y); u.h[2] = f2bf(a.z); u.h[3] = f2bf(a.w);
        u.h[4] = f2bf(b.x); u.h[5] = f2bf(b.y); u.h[6] = f2bf(b.z); u.h[7] = f2bf(b.w);
    } else {
#pragma unroll
        for (int e = 0; e < 8; ++e)
            u.h[e] = (k0 + e < D_) ? f2bf(src[k0 + e]) : (u16)0;
    }
    *reinterpret_cast<uint4*>(&xb[(size_t)row * KP_ + k0]) = u.q;
}

// ---------------------------------------------------------------------------
// K0: weight prep + combined bias (b_ih1 + b_hh1 for r,z; b_ih1 for n).
// ---------------------------------------------------------------------------
__global__ __launch_bounds__(256) void k0_prep(
    const float* __restrict__ w_ih1, const float* __restrict__ w_hh1,
    const float* __restrict__ b_ih1, const float* __restrict__ b_hh1,
    const float* __restrict__ w2f, const float* __restrict__ w2b,
    const float* __restrict__ wc1,
    u16* __restrict__ wihb, u16* __restrict__ whpk,
    u16* __restrict__ w2ft, u16* __restrict__ w2bt, u16* __restrict__ wc1t,
    float* __restrict__ biasc)
{
    int y = blockIdx.y;
    int tid = blockIdx.x * 256 + threadIdx.x;
    if (y == 0) {
        if (tid < G_ * KP_) {
            int g = tid / KP_, k = tid % KP_;
            wihb[tid] = (k < D_) ? f2bf(w_ih1[g * D_ + k]) : (u16)0;
        }
    } else if (y == 1) {
        if (tid < 48 * 8 * 64) {
            int lane = tid & 63;
            int ks = (tid >> 6) & 7;
            int nt = tid >> 9;
            int g  = nt * 16 + (lane & 15);
            int kb = ks * 32 + ((lane >> 4) << 3);
            union { u16 h[8]; uint4 q; } u;
#pragma unroll
            for (int e = 0; e < 8; ++e) u.h[e] = f2bf(w_hh1[g * H_ + kb + e]);
            *reinterpret_cast<uint4*>(&whpk[(size_t)tid * 8]) = u.q;
        }
    } else if (y == 2 || y == 3) {
        if (tid < G_ * H_) {
            int k = tid / G_, g = tid % G_;
            const float* src = (y == 2) ? w2f : w2b;
            u16* dst = (y == 2) ? w2ft : w2bt;
            dst[tid] = f2bf(src[g * H_ + k]);
        }
    } else {
        if (tid < 512 * 256) {
            int k = tid / 256, o = tid % 256;
            wc1t[tid] = f2bf(wc1[o * 512 + k]);
        }
        if (tid < G_)
            biasc[tid] = b_ih1[tid] + (tid < 2 * H_ ? b_hh1[tid] : 0.f);
    }
}

// ---------------------------------------------------------------------------
// K1 (round-8 version): xgw = (xb @ wihb^T + biasc), bf16 MFMA, 128x128 tile.
// Output [t][n][3 gates][128 words] u32; word g*128+wv8*16+c packs the bf16
// pair (unit wv8*32+c, unit wv8*32+16+c). Coalesced u32 stores.
// ---------------------------------------------------------------------------
__global__ __launch_bounds__(256) void k1_xgemm(
    const u16* __restrict__ xb, const u16* __restrict__ wihb,
    const float* __restrict__ biasc, u32* __restrict__ xgw)
{
    __shared__ alignas(16) u16 As[128 * 40];
    __shared__ alignas(16) u16 Bs[128 * 40];
    const int tid = threadIdx.x;
    const int l = tid & 63, wv = tid >> 6;
    const int wrow = wv >> 1, wcol = wv & 1;
    const int row0 = blockIdx.x * 128, col0 = blockIdx.y * 128;

    f32x4 acc[4][4];
#pragma unroll
    for (int i = 0; i < 4; ++i)
#pragma unroll
        for (int j = 0; j < 4; ++j) acc[i][j] = (f32x4){0.f, 0.f, 0.f, 0.f};

    const int ar = tid >> 1, ah = tid & 1;
    const u16* xrow  = xb + (size_t)(row0 + ar) * KP_;
    const u16* wrowp = wihb + (size_t)(col0 + ar) * KP_;

    for (int k0 = 0; k0 < KP_; k0 += 32) {
        *reinterpret_cast<uint4*>(&As[ar * 40 + ah * 16]) =
            *reinterpret_cast<const uint4*>(xrow + k0 + ah * 16);
        *reinterpret_cast<uint4*>(&As[ar * 40 + ah * 16 + 8]) =
            *reinterpret_cast<const uint4*>(xrow + k0 + ah * 16 + 8);
        *reinterpret_cast<uint4*>(&Bs[ar * 40 + ah * 16]) =
            *reinterpret_cast<const uint4*>(wrowp + k0 + ah * 16);
        *reinterpret_cast<uint4*>(&Bs[ar * 40 + ah * 16 + 8]) =
            *reinterpret_cast<const uint4*>(wrowp + k0 + ah * 16 + 8);
        __syncthreads();

        short8 af[4], bf[4];
#pragma unroll
        for (int fi = 0; fi < 4; ++fi)
            af[fi] = *reinterpret_cast<const short8*>(
                &As[(wrow * 64 + fi * 16 + (l & 15)) * 40 + ((l >> 4) << 3)]);
#pragma unroll
        for (int fj = 0; fj < 4; ++fj)
            bf[fj] = *reinterpret_cast<const short8*>(
                &Bs[(wcol * 64 + fj * 16 + (l & 15)) * 40 + ((l >> 4) << 3)]);
#pragma unroll
        for (int fi = 0; fi < 4; ++fi)
#pragma unroll
            for (int fj = 0; fj < 4; ++fj)
                acc[fi][fj] = __builtin_amdgcn_mfma_f32_16x16x32_bf16(
                    af[fi], bf[fj], acc[fi][fj], 0, 0, 0);
        __syncthreads();
    }

    float bias[4];
#pragma unroll
    for (int fj = 0; fj < 4; ++fj)
        bias[fj] = biasc[col0 + wcol * 64 + fj * 16 + (l & 15)];
#pragma unroll
    for (int fi = 0; fi < 4; ++fi)
#pragma unroll
        for (int fjp = 0; fjp < 2; ++fjp) {
            const int cg0 = col0 + wcol * 64 + fjp * 32;     // a=0,c=0 col
            const int g = cg0 >> 8;
            const int wv8 = (cg0 & 255) >> 5;
            const int word = g * 128 + wv8 * 16 + (l & 15);
#pragma unroll
            for (int q = 0; q < 4; ++q) {
                const int row = row0 + wrow * 64 + fi * 16 + ((l >> 4) << 2) + q;
                const int t = row & 63, n = row >> 6;
                const u32 lo = f2bf(acc[fi][2 * fjp][q] + bias[2 * fjp]);
                const u32 hi = f2bf(acc[fi][2 * fjp + 1][q] + bias[2 * fjp + 1]);
                xgw[((size_t)t * NROW + n) * 384 + word] = lo | (hi << 16);
            }
        }
}

// ---------------------------------------------------------------------------
// K2 v10: 32 blocks x 16 rows, 256 thr (4 waves, 1/EU). Same structure as
// verified round-12 kernel, but the 8 r/z-gate MFMAs are INLINE ASM with an
// "a" (AGPR) B-operand — the weights are consumed in place, making the
// v_accvgpr_read copy tax (768 moves/step, the round-12 VALU excess)
// structurally impossible. Manual hazard s_nops (asm is opaque to the
// hazard recognizer), sandwiched in sched_barrier(0).
// ---------------------------------------------------------------------------
__global__ __launch_bounds__(256)
__attribute__((amdgpu_waves_per_eu(1, 1)))
void k2_gru(const u32* __restrict__ xgw, const u16* __restrict__ whpk,
            const float* __restrict__ b_hh, float* __restrict__ mid)
{
    __shared__ u16 hb[2][16 * 264];        // ping-pong, 16,896 B
    const int tid = threadIdx.x;
    const int l = tid & 63, wv = tid >> 6;   // wv in [0,4)
    const int n0 = blockIdx.x * 16;
    const int c = l & 15, rgrp = l >> 4;
    const int arow = c, klo = rgrp << 3;

    // wave owns units [64wv, 64wv+64): tile m = g*4+j, nt = g*16 + 4wv + j.
    // AGPR: m 0..7 (gates r,z).  VGPR: m 8..11 (gate n).
    short8 wa[8][8];
#pragma unroll
    for (int m = 0; m < 8; ++m) {
        const int nt = (m >> 2) * 16 + 4 * wv + (m & 3);
#pragma unroll
        for (int ks = 0; ks < 8; ++ks)
            wa[m][ks] = *reinterpret_cast<const short8*>(
                &whpk[(size_t)((nt * 8 + ks) * 64 + l) * 8]);
    }
    short8 wn[4][8];
#pragma unroll
    for (int m = 0; m < 4; ++m) {
        const int nt = 32 + 4 * wv + m;
#pragma unroll
        for (int ks = 0; ks < 8; ++ks)
            wn[m][ks] = *reinterpret_cast<const short8*>(
                &whpk[(size_t)((nt * 8 + ks) * 64 + l) * 8]);
    }
    // one-time pins: asm-defined => rematerialization illegal.
    asm volatile("" :
        "+a"(wa[0][0]),"+a"(wa[0][1]),"+a"(wa[0][2]),"+a"(wa[0][3]),
        "+a"(wa[0][4]),"+a"(wa[0][5]),"+a"(wa[0][6]),"+a"(wa[0][7]),
        "+a"(wa[1][0]),"+a"(wa[1][1]),"+a"(wa[1][2]),"+a"(wa[1][3]),
        "+a"(wa[1][4]),"+a"(wa[1][5]),"+a"(wa[1][6]),"+a"(wa[1][7]));
    asm volatile("" :
        "+a"(wa[2][0]),"+a"(wa[2][1]),"+a"(wa[2][2]),"+a"(wa[2][3]),
        "+a"(wa[2][4]),"+a"(wa[2][5]),"+a"(wa[2][6]),"+a"(wa[2][7]),
        "+a"(wa[3][0]),"+a"(wa[3][1]),"+a"(wa[3][2]),"+a"(wa[3][3]),
        "+a"(wa[3][4]),"+a"(wa[3][5]),"+a"(wa[3][6]),"+a"(wa[3][7]));
    asm volatile("" :
        "+a"(wa[4][0]),"+a"(wa[4][1]),"+a"(wa[4][2]),"+a"(wa[4][3]),
        "+a"(wa[4][4]),"+a"(wa[4][5]),"+a"(wa[4][6]),"+a"(wa[4][7]),
        "+a"(wa[5][0]),"+a"(wa[5][1]),"+a"(wa[5][2]),"+a"(wa[5][3]),
        "+a"(wa[5][4]),"+a"(wa[5][5]),"+a"(wa[5][6]),"+a"(wa[5][7]));
    asm volatile("" :
        "+a"(wa[6][0]),"+a"(wa[6][1]),"+a"(wa[6][2]),"+a"(wa[6][3]),
        "+a"(wa[6][4]),"+a"(wa[6][5]),"+a"(wa[6][6]),"+a"(wa[6][7]),
        "+a"(wa[7][0]),"+a"(wa[7][1]),"+a"(wa[7][2]),"+a"(wa[7][3]),
        "+a"(wa[7][4]),"+a"(wa[7][5]),"+a"(wa[7][6]),"+a"(wa[7][7]));
    asm volatile("" :
        "+v"(wn[0][0]),"+v"(wn[0][1]),"+v"(wn[0][2]),"+v"(wn[0][3]),
        "+v"(wn[0][4]),"+v"(wn[0][5]),"+v"(wn[0][6]),"+v"(wn[0][7]),
        "+v"(wn[1][0]),"+v"(wn[1][1]),"+v"(wn[1][2]),"+v"(wn[1][3]),
        "+v"(wn[1][4]),"+v"(wn[1][5]),"+v"(wn[1][6]),"+v"(wn[1][7]));
    asm volatile("" :
        "+v"(wn[2][0]),"+v"(wn[2][1]),"+v"(wn[2][2]),"+v"(wn[2][3]),
        "+v"(wn[2][4]),"+v"(wn[2][5]),"+v"(wn[2][6]),"+v"(wn[2][7]),
        "+v"(wn[3][0]),"+v"(wn[3][1]),"+v"(wn[3][2]),"+v"(wn[3][3]),
        "+v"(wn[3][4]),"+v"(wn[3][5]),"+v"(wn[3][6]),"+v"(wn[3][7]));

    for (int i = tid; i < 2 * 16 * 264 / 2; i += 256)
        reinterpret_cast<u32*>(hb)[i] = 0;

    float bhn[4];
#pragma unroll
    for (int j = 0; j < 4; ++j)
        bhn[j] = b_hh[512 + 64 * wv + 16 * j + c];
    float h[4][4] = {};

    // advancing per-lane base pointers (addressing via offset: immediates)
    const u32 stepw = (u32)NROW * 384;
    const u32* bp0 = xgw + (u32)(n0 + rgrp * 4) * 384 + c;   // rows q=0,1
    const u32* bp1 = bp0 + 2 * 384;                          // rows q=2,3

    // prologue: load t=0 gates (24 u32/lane)
    u32 xw[3][2][4];
#pragma unroll
    for (int g = 0; g < 3; ++g)
#pragma unroll
        for (int pp = 0; pp < 2; ++pp) {
            const int o = g * 128 + (2 * wv + pp) * 16;
            xw[g][pp][0] = bp0[o];
            xw[g][pp][1] = bp0[384 + o];
            xw[g][pp][2] = bp1[o];
            xw[g][pp][3] = bp1[384 + o];
        }

    __syncthreads();

    int p = 0;
    for (int t = 0; t < T_; ++t) {
        // ---- MFMA phase: hg = h @ W (12 tiles), weights all in regs ----
        const u16* hbr = hb[p];
        f32x4 acc[12];
#pragma unroll
        for (int m = 0; m < 12; ++m) acc[m] = (f32x4){0.f, 0.f, 0.f, 0.f};
        // hazard: VALU acc-init -> asm-MFMA srcC read (2 wait states)
        __builtin_amdgcn_sched_barrier(0);
        asm volatile("s_nop 3");
        __builtin_amdgcn_sched_barrier(0);
        __builtin_amdgcn_s_setprio(1);
#pragma unroll
        for (int ks = 0; ks < 8; ++ks) {
            const short8 afr = *reinterpret_cast<const short8*>(
                &hbr[arow * 264 + ks * 32 + klo]);
#pragma unroll
            for (int m = 0; m < 8; ++m)
                asm("v_mfma_f32_16x16x32_bf16 %0, %1, %2, %0"
                    : "+v"(acc[m]) : "v"(afr), "a"(wa[m][ks]));
#pragma unroll
            for (int m = 0; m < 4; ++m)
                acc[8 + m] = __builtin_amdgcn_mfma_f32_16x16x32_bf16(
                    afr, wn[m][ks], acc[8 + m], 0, 0, 0);
        }
        __builtin_amdgcn_s_setprio(0);
        // hazard: asm-MFMA write acc -> VALU read acc (up to ~11 cycles)
        __builtin_amdgcn_sched_barrier(0);
        asm volatile("s_nop 7\n\ts_nop 7");
        __builtin_amdgcn_sched_barrier(0);

        // ---- update: 16 gate-triplets per lane, all in-lane ----
        u16* hbw = hb[p ^ 1];
#pragma unroll
        for (int j = 0; j < 4; ++j) {
            const int pw = j >> 1, shv = (j & 1) << 4;
#pragma unroll
            for (int q = 0; q < 4; ++q) {
                const float xr = bf2f((u16)(xw[0][pw][q] >> shv));
                const float xz = bf2f((u16)(xw[1][pw][q] >> shv));
                const float xn = bf2f((u16)(xw[2][pw][q] >> shv));
                const float rg = fsigm(xr + acc[j][q]);
                const float zg = fsigm(xz + acc[4 + j][q]);
                const float ng = ftanh(xn + rg * (acc[8 + j][q] + bhn[j]));
                h[j][q] = zg * (h[j][q] - ng) + ng;
                hbw[(rgrp * 4 + q) * 264 + 64 * wv + 16 * j + c] = f2bf(h[j][q]);
            }
        }

        // ---- issue next step's gate loads (cover: barrier + MFMA phase) ----
        bp0 += stepw; bp1 += stepw;   // last iter reads past t=63: mapped (xb)
#pragma unroll
        for (int g = 0; g < 3; ++g)
#pragma unroll
            for (int pp = 0; pp < 2; ++pp) {
                const int o = g * 128 + (2 * wv + pp) * 16;
                xw[g][pp][0] = bp0[o];
                xw[g][pp][1] = bp0[384 + o];
                xw[g][pp][2] = bp1[o];
                xw[g][pp][3] = bp1[384 + o];
            }

        // single barrier per step (lgkm only; vmcnt stays in flight)
        asm volatile("s_waitcnt lgkmcnt(0)" ::: "memory");
        __builtin_amdgcn_sched_barrier(0);
        __builtin_amdgcn_s_barrier();
        __builtin_amdgcn_sched_barrier(0);
        p ^= 1;
    }

#pragma unroll
    for (int j = 0; j < 4; ++j)
#pragma unroll
        for (int q = 0; q < 4; ++q)
            mid[(size_t)(n0 + rgrp * 4 + q) * H_ + 64 * wv + 16 * j + c] = h[j][q];
}

// ---------------------------------------------------------------------------
// K3: head. (unchanged)
// ---------------------------------------------------------------------------
__global__ __launch_bounds__(256) void k3_head(
    const float* __restrict__ mid,
    const u16* __restrict__ w2ft, const u16* __restrict__ w2bt,
    const float* __restrict__ b_ih2f, const float* __restrict__ b_hh2f,
    const float* __restrict__ b_ih2b, const float* __restrict__ b_hh2b,
    const u16* __restrict__ wc1t, const float* __restrict__ bc1,
    const float* __restrict__ wc2, const float* __restrict__ bc2,
    float* __restrict__ out)
{
    __shared__ float m[4][H_];
    __shared__ float xg2[2][4][G_];
    __shared__ float emb[4][512];
    __shared__ float hid[4][H_];
    int tid = threadIdx.x;
    int r0 = blockIdx.x * 4;

    for (int i = tid; i < 4 * H_; i += 256) {
        int r = i >> 8, k = i & 255;
        m[r][k] = mid[(size_t)(r0 + r) * H_ + k];
    }
    __syncthreads();

    const int g0 = tid, g1 = tid + 256, g2 = tid + 512;
    float bf0 = b_ih2f[g0] + b_hh2f[g0];
    float bf1 = b_ih2f[g1] + b_hh2f[g1];
    float bf2v = b_ih2f[g2];
    float bb0 = b_ih2b[g0] + b_hh2b[g0];
    float bb1 = b_ih2b[g1] + b_hh2b[g1];
    float bb2v = b_ih2b[g2];
    float af[4][3], ab[4][3];
#pragma unroll
    for (int r = 0; r < 4; ++r) {
        af[r][0] = bf0; af[r][1] = bf1; af[r][2] = bf2v;
        ab[r][0] = bb0; ab[r][1] = bb1; ab[r][2] = bb2v;
    }
#pragma unroll 4
    for (int k = 0; k < H_; ++k) {
        float wf0 = bf2f(w2ft[k * G_ + g0]);
        float wf1 = bf2f(w2ft[k * G_ + g1]);
        float wf2 = bf2f(w2ft[k * G_ + g2]);
        float wb0 = bf2f(w2bt[k * G_ + g0]);
        float wb1 = bf2f(w2bt[k * G_ + g1]);
        float wb2 = bf2f(w2bt[k * G_ + g2]);
#pragma unroll
        for (int r = 0; r < 4; ++r) {
            float mm = m[r][k];
            af[r][0] += mm * wf0; af[r][1] += mm * wf1; af[r][2] += mm * wf2;
            ab[r][0] += mm * wb0; ab[r][1] += mm * wb1; ab[r][2] += mm * wb2;
        }
    }
#pragma unroll
    for (int r = 0; r < 4; ++r) {
        xg2[0][r][g0] = af[r][0]; xg2[0][r][g1] = af[r][1]; xg2[0][r][g2] = af[r][2];
        xg2[1][r][g0] = ab[r][0]; xg2[1][r][g1] = ab[r][1]; xg2[1][r][g2] = ab[r][2];
    }
    __syncthreads();

    {
        const int j = tid;
        float bnf = b_hh2f[512 + j], bnb = b_hh2b[512 + j];
#pragma unroll
        for (int r = 0; r < 4; ++r) {
            float rg = sigm(xg2[0][r][j]);
            float zg = sigm(xg2[0][r][256 + j]);
            float ng = tanhf(xg2[0][r][512 + j] + rg * bnf);
            emb[r][j] = (1.f - zg) * ng;
            rg = sigm(xg2[1][r][j]);
            zg = sigm(xg2[1][r][256 + j]);
            ng = tanhf(xg2[1][r][512 + j] + rg * bnb);
            emb[r][256 + j] = (1.f - zg) * ng;
        }
    }
    __syncthreads();

    {
        const int o = tid;
        float acc[4];
        float b = bc1[o];
#pragma unroll
        for (int r = 0; r < 4; ++r) acc[r] = b;
#pragma unroll 4
        for (int k = 0; k < 512; ++k) {
            float w = bf2f(wc1t[k * H_ + o]);
#pragma unroll
            for (int r = 0; r < 4; ++r) acc[r] += emb[r][k] * w;
        }
#pragma unroll
        for (int r = 0; r < 4; ++r) {
            float pre = acc[r];
            hid[r][o] = pre >= 0.f ? pre : 0.1f * pre;
        }
    }
    __syncthreads();

    {
        int grp = tid >> 5, lane = tid & 31;
        int r = grp >> 1, cc = grp & 1;
        float s = 0.f;
        for (int k = lane; k < H_; k += 32) s += hid[r][k] * wc2[cc * H_ + k];
#pragma unroll
        for (int msk = 16; msk >= 1; msk >>= 1) s += __shfl_xor(s, msk, 32);
        if (lane == 0) out[(size_t)(r0 + r) * 2 + cc] = s + bc2[cc];
    }
}

// ---------------------------------------------------------------------------
extern "C" void kernel_launch(void* const* d_in, const int* in_sizes, int n_in,
                              void* d_out, int out_size, void* d_ws, size_t ws_size,
                              hipStream_t stream)
{
    const float* x      = (const float*)d_in[0];
    const float* w_ih1  = (const float*)d_in[1];
    const float* w_hh1  = (const float*)d_in[2];
    const float* b_ih1  = (const float*)d_in[3];
    const float* b_hh1  = (const float*)d_in[4];
    const float* w_ih2f = (const float*)d_in[5];
    const float* b_ih2f = (const float*)d_in[7];
    const float* b_hh2f = (const float*)d_in[8];
    const float* w_ih2b = (const float*)d_in[9];
    const float* b_ih2b = (const float*)d_in[11];
    const float* b_hh2b = (const float*)d_in[12];
    const float* wc1    = (const float*)d_in[13];
    const float* bc1    = (const float*)d_in[14];
    const float* wc2    = (const float*)d_in[15];
    const float* bc2    = (const float*)d_in[16];
    float* out = (float*)d_out;

    char* p = (char*)d_ws;
    u32* xgw  = (u32*)p;  p += (size_t)M_ * 384 * 4;         // 48 MB [t][n][3][128]u32
    u16* xb   = (u16*)p;  p += (size_t)M_ * KP_ * 2;         // 20 MB
    u16* wihb = (u16*)p;  p += (size_t)G_ * KP_ * 2;         // 480 KB
    u16* whpk = (u16*)p;  p += (size_t)48 * 8 * 64 * 8 * 2;  // 384 KB
    u16* w2ft = (u16*)p;  p += (size_t)G_ * H_ * 2;
    u16* w2bt = (u16*)p;  p += (size_t)G_ * H_ * 2;
    u16* wc1t = (u16*)p;  p += (size_t)512 * 256 * 2;
    float* mid = (float*)p; p += (size_t)NROW * H_ * 4;
    float* biasc = (float*)p; p += (size_t)G_ * 4;

    kx_cast<<<M_ * 40 / 256, 256, 0, stream>>>(x, xb);
    k0_prep<<<dim3(960, 5), 256, 0, stream>>>(w_ih1, w_hh1, b_ih1, b_hh1,
                                              w_ih2f, w_ih2b, wc1,
                                              wihb, whpk, w2ft, w2bt, wc1t, biasc);
    k1_xgemm<<<dim3(M_ / 128, G_ / 128), 256, 0, stream>>>(xb, wihb, biasc, xgw);
    k2_gru<<<32, 256, 0, stream>>>(xgw, whpk, b_hh1, mid);
    k3_head<<<128, 256, 0, stream>>>(mid, w2ft, w2bt, b_ih2f, b_hh2f,
                                     b_ih2b, b_hh2b, wc1t, bc1, wc2, bc2, out);
}

// Round 14
// 239.975 us; speedup vs baseline: 1.2459x; 1.1132x over previous
//
#include <hip/hip_runtime.h>
#include <hip/hip_bf16.h>

typedef unsigned short u16;
typedef unsigned int u32;
using short8 = __attribute__((ext_vector_type(8))) short;
using f32x4  = __attribute__((ext_vector_type(4))) float;

#define T_   64
#define D_   300
#define H_   256
#define G_   768            // 3H
#define NROW 512            // useful sequences (s==2)
#define M_   (NROW * T_)    // 32768
#define KP_  320            // K=300 padded to 320 for MFMA

__device__ __forceinline__ float bf2f(u16 v) {
    union { u32 u; float f; } x; x.u = ((u32)v) << 16; return x.f;
}
__device__ __forceinline__ float bf2f_lo(u32 w) {
    union { u32 u; float f; } x; x.u = w << 16; return x.f;
}
__device__ __forceinline__ float bf2f_hi(u32 w) {
    union { u32 u; float f; } x; x.u = w & 0xFFFF0000u; return x.f;
}
__device__ __forceinline__ u16 f2bf(float f) {
    union { u32 u; float f; } x; x.f = f;
    u32 u = x.u;
    u32 r = (u + 0x7FFFu + ((u >> 16) & 1u)) >> 16;   // RNE
    return (u16)r;
}
__device__ __forceinline__ float frcp(float x) {
    float r; asm("v_rcp_f32 %0, %1" : "=v"(r) : "v"(x)); return r;
}
__device__ __forceinline__ float fsigm(float x) { return frcp(1.f + __expf(-x)); }
__device__ __forceinline__ float ftanh(float x) {
    return 1.f - 2.f * frcp(1.f + __expf(2.f * x));
}
__device__ __forceinline__ float sigm(float x) { return 1.f / (1.f + expf(-x)); }

// ---------------------------------------------------------------------------
// K0: weight prep + combined bias (b_ih1 + b_hh1 for r,z; b_ih1 for n).
// ---------------------------------------------------------------------------
__global__ __launch_bounds__(256) void k0_prep(
    const float* __restrict__ w_ih1, const float* __restrict__ w_hh1,
    const float* __restrict__ b_ih1, const float* __restrict__ b_hh1,
    const float* __restrict__ w2f, const float* __restrict__ w2b,
    const float* __restrict__ wc1,
    u16* __restrict__ wihb, u16* __restrict__ whpk,
    u16* __restrict__ w2ft, u16* __restrict__ w2bt, u16* __restrict__ wc1t,
    float* __restrict__ biasc)
{
    int y = blockIdx.y;
    int tid = blockIdx.x * 256 + threadIdx.x;
    if (y == 0) {
        if (tid < G_ * KP_) {
            int g = tid / KP_, k = tid % KP_;
            wihb[tid] = (k < D_) ? f2bf(w_ih1[g * D_ + k]) : (u16)0;
        }
    } else if (y == 1) {
        if (tid < 48 * 8 * 64) {
            int lane = tid & 63;
            int ks = (tid >> 6) & 7;
            int nt = tid >> 9;
            int g  = nt * 16 + (lane & 15);
            int kb = ks * 32 + ((lane >> 4) << 3);
            union { u16 h[8]; uint4 q; } u;
#pragma unroll
            for (int e = 0; e < 8; ++e) u.h[e] = f2bf(w_hh1[g * H_ + kb + e]);
            *reinterpret_cast<uint4*>(&whpk[(size_t)tid * 8]) = u.q;
        }
    } else if (y == 2 || y == 3) {
        if (tid < G_ * H_) {
            int k = tid / G_, g = tid % G_;
            const float* src = (y == 2) ? w2f : w2b;
            u16* dst = (y == 2) ? w2ft : w2bt;
            dst[tid] = f2bf(src[g * H_ + k]);
        }
    } else {
        if (tid < 512 * 256) {
            int k = tid / 256, o = tid % 256;
            wc1t[tid] = f2bf(wc1[o * 512 + k]);
        }
        if (tid < G_)
            biasc[tid] = b_ih1[tid] + (tid < 2 * H_ ? b_hh1[tid] : 0.f);
    }
}

// ---------------------------------------------------------------------------
// K1 (kx fused): xgw = (x[:,2] @ wihb^T + biasc), bf16 MFMA, 128x128 tile.
// A staged DIRECTLY from fp32 x with in-staging bf16 cvt (round-3..5 path,
// verified) — kx_cast kernel and the 20 MB xb buffer are eliminated.
// Output [t][n][3 gates][128 words] u32; word g*128+wv8*16+c packs the bf16
// pair (unit wv8*32+c, unit wv8*32+16+c). Coalesced u32 stores.
// ---------------------------------------------------------------------------
__global__ __launch_bounds__(256) void k1_xgemm(
    const float* __restrict__ x, const u16* __restrict__ wihb,
    const float* __restrict__ biasc, u32* __restrict__ xgw)
{
    __shared__ alignas(16) u16 As[128 * 40];
    __shared__ alignas(16) u16 Bs[128 * 40];
    const int tid = threadIdx.x;
    const int l = tid & 63, wv = tid >> 6;
    const int wrow = wv >> 1, wcol = wv & 1;
    const int row0 = blockIdx.x * 128, col0 = blockIdx.y * 128;

    f32x4 acc[4][4];
#pragma unroll
    for (int i = 0; i < 4; ++i)
#pragma unroll
        for (int j = 0; j < 4; ++j) acc[i][j] = (f32x4){0.f, 0.f, 0.f, 0.f};

    const int ar = tid >> 1, ah = tid & 1;
    const int grow = row0 + ar;
    const int nn = grow >> 6, tt = grow & 63;
    const float* xrow = x + (size_t)(nn * 256 + 128 + tt) * D_;
    const u16* wrowp = wihb + (size_t)(col0 + ar) * KP_;

    for (int k0 = 0; k0 < KP_; k0 += 32) {
        // ---- stage A (fp32 -> bf16), 16 shorts/thread ----
        union { u16 h[16]; uint4 q[2]; } u;
        const int kb = k0 + ah * 16;
        if (kb + 15 < D_) {
            const float4 v0 = *reinterpret_cast<const float4*>(xrow + kb);
            const float4 v1 = *reinterpret_cast<const float4*>(xrow + kb + 4);
            const float4 v2 = *reinterpret_cast<const float4*>(xrow + kb + 8);
            const float4 v3 = *reinterpret_cast<const float4*>(xrow + kb + 12);
            u.h[0] = f2bf(v0.x); u.h[1] = f2bf(v0.y); u.h[2] = f2bf(v0.z); u.h[3] = f2bf(v0.w);
            u.h[4] = f2bf(v1.x); u.h[5] = f2bf(v1.y); u.h[6] = f2bf(v1.z); u.h[7] = f2bf(v1.w);
            u.h[8] = f2bf(v2.x); u.h[9] = f2bf(v2.y); u.h[10] = f2bf(v2.z); u.h[11] = f2bf(v2.w);
            u.h[12] = f2bf(v3.x); u.h[13] = f2bf(v3.y); u.h[14] = f2bf(v3.z); u.h[15] = f2bf(v3.w);
        } else {
#pragma unroll
            for (int e = 0; e < 16; ++e) {
                int k = kb + e;
                u.h[e] = (k < D_) ? f2bf(xrow[k]) : (u16)0;
            }
        }
        *reinterpret_cast<uint4*>(&As[ar * 40 + ah * 16]) = u.q[0];
        *reinterpret_cast<uint4*>(&As[ar * 40 + ah * 16 + 8]) = u.q[1];
        // ---- stage B (already bf16), 16 shorts/thread ----
        *reinterpret_cast<uint4*>(&Bs[ar * 40 + ah * 16]) =
            *reinterpret_cast<const uint4*>(wrowp + k0 + ah * 16);
        *reinterpret_cast<uint4*>(&Bs[ar * 40 + ah * 16 + 8]) =
            *reinterpret_cast<const uint4*>(wrowp + k0 + ah * 16 + 8);
        __syncthreads();

        short8 af[4], bf[4];
#pragma unroll
        for (int fi = 0; fi < 4; ++fi)
            af[fi] = *reinterpret_cast<const short8*>(
                &As[(wrow * 64 + fi * 16 + (l & 15)) * 40 + ((l >> 4) << 3)]);
#pragma unroll
        for (int fj = 0; fj < 4; ++fj)
            bf[fj] = *reinterpret_cast<const short8*>(
                &Bs[(wcol * 64 + fj * 16 + (l & 15)) * 40 + ((l >> 4) << 3)]);
#pragma unroll
        for (int fi = 0; fi < 4; ++fi)
#pragma unroll
            for (int fj = 0; fj < 4; ++fj)
                acc[fi][fj] = __builtin_amdgcn_mfma_f32_16x16x32_bf16(
                    af[fi], bf[fj], acc[fi][fj], 0, 0, 0);
        __syncthreads();
    }

    float bias[4];
#pragma unroll
    for (int fj = 0; fj < 4; ++fj)
        bias[fj] = biasc[col0 + wcol * 64 + fj * 16 + (l & 15)];
#pragma unroll
    for (int fi = 0; fi < 4; ++fi)
#pragma unroll
        for (int fjp = 0; fjp < 2; ++fjp) {
            const int cg0 = col0 + wcol * 64 + fjp * 32;     // a=0,c=0 col
            const int g = cg0 >> 8;
            const int wv8 = (cg0 & 255) >> 5;
            const int word = g * 128 + wv8 * 16 + (l & 15);
#pragma unroll
            for (int q = 0; q < 4; ++q) {
                const int row = row0 + wrow * 64 + fi * 16 + ((l >> 4) << 2) + q;
                const int t = row & 63, n = row >> 6;
                const u32 lo = f2bf(acc[fi][2 * fjp][q] + bias[2 * fjp]);
                const u32 hi = f2bf(acc[fi][2 * fjp + 1][q] + bias[2 * fjp + 1]);
                xgw[((size_t)t * NROW + n) * 384 + word] = lo | (hi << 16);
            }
        }
}

// ---------------------------------------------------------------------------
// K2 (round-8 verbatim — empirical best of 6 structural variants, 114 µs):
// 64 blocks x 8 rows, 512 thr (8 waves, 2/EU). Weights ks0-5 AGPR-pinned,
// ks6-7 LDS. Lanes 0-31 a=0, lanes 32-63 a=1 via shfl. xg prefetched one
// full step ahead. One barrier/step.
// ---------------------------------------------------------------------------
__global__ __launch_bounds__(512)
__attribute__((amdgpu_waves_per_eu(2, 2)))
void k2_gru(const u32* __restrict__ xgw, const u16* __restrict__ whpk,
            const float* __restrict__ b_hh, float* __restrict__ mid)
{
    extern __shared__ u16 smem[];
    u16* wl = smem;                        // ks6-7: 48*2*64*8 u16 = 98304 B
    u16* hb = smem + 48 * 2 * 64 * 8;      // ping-pong 2 x 16*264 u16
    const int tid = threadIdx.x;
    const int l = tid & 63, wv = tid >> 6;   // wv in [0,8)
    const int n0 = blockIdx.x * 8;
    const int c = l & 15, rgrp = l >> 4;
    const int arow = c, klo = rgrp << 3;
    const int aSel = rgrp >> 1;              // 0: lanes 0-31, 1: lanes 32-63
    const int rbase = (rgrp & 1) * 4;        // rows rbase..rbase+3
    const int u = wv * 32 + aSel * 16 + c;   // hidden unit this lane updates

    // weights ks 0..5 (36 x short8 = 144 regs), pinned to AGPRs
    short8 wr[6][6];
#pragma unroll
    for (int gt = 0; gt < 3; ++gt)
#pragma unroll
        for (int a = 0; a < 2; ++a) {
            const int nt = gt * 16 + wv * 2 + a;
#pragma unroll
            for (int ks = 0; ks < 6; ++ks)
                wr[gt * 2 + a][ks] = *reinterpret_cast<const short8*>(
                    &whpk[(size_t)((nt * 8 + ks) * 64 + l) * 8]);
        }
    asm volatile("" :
        "+a"(wr[0][0]),"+a"(wr[0][1]),"+a"(wr[0][2]),"+a"(wr[0][3]),"+a"(wr[0][4]),"+a"(wr[0][5]),
        "+a"(wr[1][0]),"+a"(wr[1][1]),"+a"(wr[1][2]),"+a"(wr[1][3]),"+a"(wr[1][4]),"+a"(wr[1][5]),
        "+a"(wr[2][0]),"+a"(wr[2][1]),"+a"(wr[2][2]),"+a"(wr[2][3]),"+a"(wr[2][4]),"+a"(wr[2][5]));
    asm volatile("" :
        "+a"(wr[3][0]),"+a"(wr[3][1]),"+a"(wr[3][2]),"+a"(wr[3][3]),"+a"(wr[3][4]),"+a"(wr[3][5]),
        "+a"(wr[4][0]),"+a"(wr[4][1]),"+a"(wr[4][2]),"+a"(wr[4][3]),"+a"(wr[4][4]),"+a"(wr[4][5]),
        "+a"(wr[5][0]),"+a"(wr[5][1]),"+a"(wr[5][2]),"+a"(wr[5][3]),"+a"(wr[5][4]),"+a"(wr[5][5]));

    // stage ks 6..7 into LDS
    for (int cc = tid; cc < 48 * 2 * 64; cc += 512) {
        const int nt = cc >> 7, j = (cc >> 6) & 1, ll = cc & 63;
        *reinterpret_cast<uint4*>(&wl[(size_t)cc * 8]) =
            *reinterpret_cast<const uint4*>(
                &whpk[(size_t)((nt * 8 + 6 + j) * 64 + ll) * 8]);
    }
    for (int i = tid; i < 2 * 16 * 264 / 2; i += 512) ((u32*)hb)[i] = 0;

    const float bhn = b_hh[512 + u];
    u32 xo[4];
#pragma unroll
    for (int q = 0; q < 4; ++q)
        xo[q] = (u32)(n0 + rbase + q) * 384 + wv * 16 + c;
    float h[4] = {0.f, 0.f, 0.f, 0.f};
    const u32 stepw = (u32)NROW * 384;

    // prologue: load t=0 gates
    u32 xa[3][4], xn2[3][4];
#pragma unroll
    for (int q = 0; q < 4; ++q) {
        xa[0][q] = xgw[xo[q]];
        xa[1][q] = xgw[xo[q] + 128];
        xa[2][q] = xgw[xo[q] + 256];
    }

    __syncthreads();

    int p = 0;
    for (int t = 0; t < T_; ++t) {
        // prefetch next step's gates (fully hidden under this step)
        const u32 tb = (u32)(t + 1 < T_ ? t + 1 : T_ - 1) * stepw;
#pragma unroll
        for (int q = 0; q < 4; ++q) {
            xn2[0][q] = xgw[tb + xo[q]];
            xn2[1][q] = xgw[tb + xo[q] + 128];
            xn2[2][q] = xgw[tb + xo[q] + 256];
        }

        // MFMA phase: read hb[p]
        const u16* hbr = hb + p * (16 * 264);
        f32x4 acc[6];
#pragma unroll
        for (int m = 0; m < 6; ++m) acc[m] = (f32x4){0.f, 0.f, 0.f, 0.f};
        __builtin_amdgcn_s_setprio(1);
#pragma unroll
        for (int ks = 0; ks < 6; ++ks) {
            const short8 afr = *reinterpret_cast<const short8*>(
                &hbr[arow * 264 + ks * 32 + klo]);
#pragma unroll
            for (int m = 0; m < 6; ++m)
                acc[m] = __builtin_amdgcn_mfma_f32_16x16x32_bf16(
                    afr, wr[m][ks], acc[m], 0, 0, 0);
        }
#pragma unroll
        for (int ks = 6; ks < 8; ++ks) {
            const short8 afr = *reinterpret_cast<const short8*>(
                &hbr[arow * 264 + ks * 32 + klo]);
#pragma unroll
            for (int gt = 0; gt < 3; ++gt)
#pragma unroll
                for (int a = 0; a < 2; ++a) {
                    const int nt2 = (gt * 16 + wv * 2 + a) * 2 + (ks - 6);
                    const short8 bfr = *reinterpret_cast<const short8*>(
                        &wl[(size_t)(nt2 * 64 + l) * 8]);
                    acc[gt * 2 + a] = __builtin_amdgcn_mfma_f32_16x16x32_bf16(
                        afr, bfr, acc[gt * 2 + a], 0, 0, 0);
                }
        }
        __builtin_amdgcn_s_setprio(0);

        // redistribute: lanes>=32 take a=1 accs from lane l-32
        float vr[4], vz[4], vn[4];
#pragma unroll
        for (int q = 0; q < 4; ++q) {
            const float r1 = __shfl(acc[1][q], l & 31);
            const float z1 = __shfl(acc[3][q], l & 31);
            const float n1 = __shfl(acc[5][q], l & 31);
            vr[q] = (l < 32) ? acc[0][q] : r1;
            vz[q] = (l < 32) ? acc[2][q] : z1;
            vn[q] = (l < 32) ? acc[4][q] : n1;
        }

        // update phase: 4 (row,unit) values per lane, all 64 lanes active
        u16* hbw = hb + (p ^ 1) * (16 * 264);
#pragma unroll
        for (int q = 0; q < 4; ++q) {
            const float xr = aSel ? bf2f_hi(xa[0][q]) : bf2f_lo(xa[0][q]);
            const float xz = aSel ? bf2f_hi(xa[1][q]) : bf2f_lo(xa[1][q]);
            const float xn = aSel ? bf2f_hi(xa[2][q]) : bf2f_lo(xa[2][q]);
            const float rg = fsigm(xr + vr[q]);
            const float zg = fsigm(xz + vz[q]);
            const float ng = ftanh(xn + rg * (vn[q] + bhn));
            h[q] = zg * (h[q] - ng) + ng;
            hbw[(rbase + q) * 264 + u] = f2bf(h[q]);
        }

        // roll prefetch regs
#pragma unroll
        for (int g = 0; g < 3; ++g)
#pragma unroll
            for (int q = 0; q < 4; ++q) xa[g][q] = xn2[g][q];

        // single barrier per step
        asm volatile("s_waitcnt lgkmcnt(0)" ::: "memory");
        __builtin_amdgcn_sched_barrier(0);
        __builtin_amdgcn_s_barrier();
        __builtin_amdgcn_sched_barrier(0);
        p ^= 1;
    }

#pragma unroll
    for (int q = 0; q < 4; ++q)
        mid[(size_t)(n0 + rbase + q) * H_ + u] = h[q];
}

// ---------------------------------------------------------------------------
// K3: head. (unchanged)
// ---------------------------------------------------------------------------
__global__ __launch_bounds__(256) void k3_head(
    const float* __restrict__ mid,
    const u16* __restrict__ w2ft, const u16* __restrict__ w2bt,
    const float* __restrict__ b_ih2f, const float* __restrict__ b_hh2f,
    const float* __restrict__ b_ih2b, const float* __restrict__ b_hh2b,
    const u16* __restrict__ wc1t, const float* __restrict__ bc1,
    const float* __restrict__ wc2, const float* __restrict__ bc2,
    float* __restrict__ out)
{
    __shared__ float m[4][H_];
    __shared__ float xg2[2][4][G_];
    __shared__ float emb[4][512];
    __shared__ float hid[4][H_];
    int tid = threadIdx.x;
    int r0 = blockIdx.x * 4;

    for (int i = tid; i < 4 * H_; i += 256) {
        int r = i >> 8, k = i & 255;
        m[r][k] = mid[(size_t)(r0 + r) * H_ + k];
    }
    __syncthreads();

    const int g0 = tid, g1 = tid + 256, g2 = tid + 512;
    float bf0 = b_ih2f[g0] + b_hh2f[g0];
    float bf1 = b_ih2f[g1] + b_hh2f[g1];
    float bf2v = b_ih2f[g2];
    float bb0 = b_ih2b[g0] + b_hh2b[g0];
    float bb1 = b_ih2b[g1] + b_hh2b[g1];
    float bb2v = b_ih2b[g2];
    float af[4][3], ab[4][3];
#pragma unroll
    for (int r = 0; r < 4; ++r) {
        af[r][0] = bf0; af[r][1] = bf1; af[r][2] = bf2v;
        ab[r][0] = bb0; ab[r][1] = bb1; ab[r][2] = bb2v;
    }
#pragma unroll 4
    for (int k = 0; k < H_; ++k) {
        float wf0 = bf2f(w2ft[k * G_ + g0]);
        float wf1 = bf2f(w2ft[k * G_ + g1]);
        float wf2 = bf2f(w2ft[k * G_ + g2]);
        float wb0 = bf2f(w2bt[k * G_ + g0]);
        float wb1 = bf2f(w2bt[k * G_ + g1]);
        float wb2 = bf2f(w2bt[k * G_ + g2]);
#pragma unroll
        for (int r = 0; r < 4; ++r) {
            float mm = m[r][k];
            af[r][0] += mm * wf0; af[r][1] += mm * wf1; af[r][2] += mm * wf2;
            ab[r][0] += mm * wb0; ab[r][1] += mm * wb1; ab[r][2] += mm * wb2;
        }
    }
#pragma unroll
    for (int r = 0; r < 4; ++r) {
        xg2[0][r][g0] = af[r][0]; xg2[0][r][g1] = af[r][1]; xg2[0][r][g2] = af[r][2];
        xg2[1][r][g0] = ab[r][0]; xg2[1][r][g1] = ab[r][1]; xg2[1][r][g2] = ab[r][2];
    }
    __syncthreads();

    {
        const int j = tid;
        float bnf = b_hh2f[512 + j], bnb = b_hh2b[512 + j];
#pragma unroll
        for (int r = 0; r < 4; ++r) {
            float rg = sigm(xg2[0][r][j]);
            float zg = sigm(xg2[0][r][256 + j]);
            float ng = tanhf(xg2[0][r][512 + j] + rg * bnf);
            emb[r][j] = (1.f - zg) * ng;
            rg = sigm(xg2[1][r][j]);
            zg = sigm(xg2[1][r][256 + j]);
            ng = tanhf(xg2[1][r][512 + j] + rg * bnb);
            emb[r][256 + j] = (1.f - zg) * ng;
        }
    }
    __syncthreads();

    {
        const int o = tid;
        float acc[4];
        float b = bc1[o];
#pragma unroll
        for (int r = 0; r < 4; ++r) acc[r] = b;
#pragma unroll 4
        for (int k = 0; k < 512; ++k) {
            float w = bf2f(wc1t[k * H_ + o]);
#pragma unroll
            for (int r = 0; r < 4; ++r) acc[r] += emb[r][k] * w;
        }
#pragma unroll
        for (int r = 0; r < 4; ++r) {
            float pre = acc[r];
            hid[r][o] = pre >= 0.f ? pre : 0.1f * pre;
        }
    }
    __syncthreads();

    {
        int grp = tid >> 5, lane = tid & 31;
        int r = grp >> 1, cc = grp & 1;
        float s = 0.f;
        for (int k = lane; k < H_; k += 32) s += hid[r][k] * wc2[cc * H_ + k];
#pragma unroll
        for (int msk = 16; msk >= 1; msk >>= 1) s += __shfl_xor(s, msk, 32);
        if (lane == 0) out[(size_t)(r0 + r) * 2 + cc] = s + bc2[cc];
    }
}

// ---------------------------------------------------------------------------
extern "C" void kernel_launch(void* const* d_in, const int* in_sizes, int n_in,
                              void* d_out, int out_size, void* d_ws, size_t ws_size,
                              hipStream_t stream)
{
    const float* x      = (const float*)d_in[0];
    const float* w_ih1  = (const float*)d_in[1];
    const float* w_hh1  = (const float*)d_in[2];
    const float* b_ih1  = (const float*)d_in[3];
    const float* b_hh1  = (const float*)d_in[4];
    const float* w_ih2f = (const float*)d_in[5];
    const float* b_ih2f = (const float*)d_in[7];
    const float* b_hh2f = (const float*)d_in[8];
    const float* w_ih2b = (const float*)d_in[9];
    const float* b_ih2b = (const float*)d_in[11];
    const float* b_hh2b = (const float*)d_in[12];
    const float* wc1    = (const float*)d_in[13];
    const float* bc1    = (const float*)d_in[14];
    const float* wc2    = (const float*)d_in[15];
    const float* bc2    = (const float*)d_in[16];
    float* out = (float*)d_out;

    char* p = (char*)d_ws;
    u32* xgw  = (u32*)p;  p += (size_t)M_ * 384 * 4;         // 48 MB [t][n][3][128]u32
    u16* wihb = (u16*)p;  p += (size_t)G_ * KP_ * 2;         // 480 KB
    u16* whpk = (u16*)p;  p += (size_t)48 * 8 * 64 * 8 * 2;  // 384 KB
    u16* w2ft = (u16*)p;  p += (size_t)G_ * H_ * 2;
    u16* w2bt = (u16*)p;  p += (size_t)G_ * H_ * 2;
    u16* wc1t = (u16*)p;  p += (size_t)512 * 256 * 2;
    float* mid = (float*)p; p += (size_t)NROW * H_ * 4;
    float* biasc = (float*)p; p += (size_t)G_ * 4;

    k0_prep<<<dim3(960, 5), 256, 0, stream>>>(w_ih1, w_hh1, b_ih1, b_hh1,
                                              w_ih2f, w_ih2b, wc1,
                                              wihb, whpk, w2ft, w2bt, wc1t, biasc);
    k1_xgemm<<<dim3(M_ / 128, G_ / 128), 256, 0, stream>>>(x, wihb, biasc, xgw);
    const int k2_lds = (48 * 2 * 64 * 8 + 2 * 16 * 264) * 2;   // 115200 B
    k2_gru<<<64, 512, k2_lds, stream>>>(xgw, whpk, b_hh1, mid);
    k3_head<<<128, 256, 0, stream>>>(mid, w2ft, w2bt, b_ih2f, b_hh2f,
                                     b_ih2b, b_hh2b, wc1t, bc1, wc2, bc2, out);
}

// Round 15
// 237.986 us; speedup vs baseline: 1.2563x; 1.0084x over previous
//
#include <hip/hip_runtime.h>
#include <hip/hip_bf16.h>

typedef unsigned short u16;
typedef unsigned int u32;
using short8 = __attribute__((ext_vector_type(8))) short;
using f32x4  = __attribute__((ext_vector_type(4))) float;

#define T_   64
#define D_   300
#define H_   256
#define G_   768            // 3H
#define NROW 512            // useful sequences (s==2)
#define M_   (NROW * T_)    // 32768
#define KP_  320            // K=300 padded to 320 for MFMA

__device__ __forceinline__ float bf2f(u16 v) {
    union { u32 u; float f; } x; x.u = ((u32)v) << 16; return x.f;
}
__device__ __forceinline__ float bf2f_lo(u32 w) {
    union { u32 u; float f; } x; x.u = w << 16; return x.f;
}
__device__ __forceinline__ float bf2f_hi(u32 w) {
    union { u32 u; float f; } x; x.u = w & 0xFFFF0000u; return x.f;
}
__device__ __forceinline__ u16 f2bf(float f) {
    union { u32 u; float f; } x; x.f = f;
    u32 u = x.u;
    u32 r = (u + 0x7FFFu + ((u >> 16) & 1u)) >> 16;   // RNE
    return (u16)r;
}
__device__ __forceinline__ float frcp(float x) {
    float r; asm("v_rcp_f32 %0, %1" : "=v"(r) : "v"(x)); return r;
}
__device__ __forceinline__ float fsigm(float x) { return frcp(1.f + __expf(-x)); }
__device__ __forceinline__ float ftanh(float x) {
    return 1.f - 2.f * frcp(1.f + __expf(2.f * x));
}
__device__ __forceinline__ float sigm(float x) { return 1.f / (1.f + expf(-x)); }

// ---------------------------------------------------------------------------
// K0: weight prep + combined bias (b_ih1 + b_hh1 for r,z; b_ih1 for n).
// ---------------------------------------------------------------------------
__global__ __launch_bounds__(256) void k0_prep(
    const float* __restrict__ w_ih1, const float* __restrict__ w_hh1,
    const float* __restrict__ b_ih1, const float* __restrict__ b_hh1,
    const float* __restrict__ w2f, const float* __restrict__ w2b,
    const float* __restrict__ wc1,
    u16* __restrict__ wihb, u16* __restrict__ whpk,
    u16* __restrict__ w2ft, u16* __restrict__ w2bt, u16* __restrict__ wc1t,
    float* __restrict__ biasc)
{
    int y = blockIdx.y;
    int tid = blockIdx.x * 256 + threadIdx.x;
    if (y == 0) {
        if (tid < G_ * KP_) {
            int g = tid / KP_, k = tid % KP_;
            wihb[tid] = (k < D_) ? f2bf(w_ih1[g * D_ + k]) : (u16)0;
        }
    } else if (y == 1) {
        if (tid < 48 * 8 * 64) {
            int lane = tid & 63;
            int ks = (tid >> 6) & 7;
            int nt = tid >> 9;
            int g  = nt * 16 + (lane & 15);
            int kb = ks * 32 + ((lane >> 4) << 3);
            union { u16 h[8]; uint4 q; } u;
#pragma unroll
            for (int e = 0; e < 8; ++e) u.h[e] = f2bf(w_hh1[g * H_ + kb + e]);
            *reinterpret_cast<uint4*>(&whpk[(size_t)tid * 8]) = u.q;
        }
    } else if (y == 2 || y == 3) {
        if (tid < G_ * H_) {
            int k = tid / G_, g = tid % G_;
            const float* src = (y == 2) ? w2f : w2b;
            u16* dst = (y == 2) ? w2ft : w2bt;
            dst[tid] = f2bf(src[g * H_ + k]);
        }
    } else {
        if (tid < 512 * 256) {
            int k = tid / 256, o = tid % 256;
            wc1t[tid] = f2bf(wc1[o * 512 + k]);
        }
        if (tid < G_)
            biasc[tid] = b_ih1[tid] + (tid < 2 * H_ ? b_hh1[tid] : 0.f);
    }
}

// ---------------------------------------------------------------------------
// K1 v3: xgw = (x[:,2] @ wihb^T + biasc), bf16 MFMA.
// 512 thr (8 waves 2x4), 128x256 tile, grid (256,3): x re-read/cvt 3x not 6x.
// Output [t][n][3 gates][128 words] u32 (unchanged packing).
// ---------------------------------------------------------------------------
__global__ __launch_bounds__(512) void k1_xgemm(
    const float* __restrict__ x, const u16* __restrict__ wihb,
    const float* __restrict__ biasc, u32* __restrict__ xgw)
{
    __shared__ alignas(16) u16 As[128 * 40];   // 10,240 B
    __shared__ alignas(16) u16 Bs[256 * 40];   // 20,480 B
    const int tid = threadIdx.x;
    const int l = tid & 63, wv = tid >> 6;       // 8 waves
    const int wrow = wv >> 2, wcol = wv & 3;     // 2 x 4
    const int row0 = blockIdx.x * 128, col0 = blockIdx.y * 256;

    f32x4 acc[4][4];
#pragma unroll
    for (int i = 0; i < 4; ++i)
#pragma unroll
        for (int j = 0; j < 4; ++j) acc[i][j] = (f32x4){0.f, 0.f, 0.f, 0.f};

    // A staging: thread -> row ar, k-segment ah*8 (8 shorts)
    const int ar = tid >> 2, ah = tid & 3;
    const int grow = row0 + ar;
    const int nn = grow >> 6, tt = grow & 63;
    const float* xrow = x + (size_t)(nn * 256 + 128 + tt) * D_;
    // B staging: thread -> col br, k-segment bh*16 (16 shorts)
    const int br = tid >> 1, bh = tid & 1;
    const u16* wrowp = wihb + (size_t)(col0 + br) * KP_;

    for (int k0 = 0; k0 < KP_; k0 += 32) {
        // ---- stage A (fp32 -> bf16), 8 shorts/thread ----
        union { u16 h[8]; uint4 q; } u;
        const int kb = k0 + ah * 8;
        if (kb + 7 < D_) {
            const float4 v0 = *reinterpret_cast<const float4*>(xrow + kb);
            const float4 v1 = *reinterpret_cast<const float4*>(xrow + kb + 4);
            u.h[0] = f2bf(v0.x); u.h[1] = f2bf(v0.y); u.h[2] = f2bf(v0.z); u.h[3] = f2bf(v0.w);
            u.h[4] = f2bf(v1.x); u.h[5] = f2bf(v1.y); u.h[6] = f2bf(v1.z); u.h[7] = f2bf(v1.w);
        } else {
#pragma unroll
            for (int e = 0; e < 8; ++e) {
                int k = kb + e;
                u.h[e] = (k < D_) ? f2bf(xrow[k]) : (u16)0;
            }
        }
        *reinterpret_cast<uint4*>(&As[ar * 40 + ah * 8]) = u.q;
        // ---- stage B (already bf16), 16 shorts/thread ----
        *reinterpret_cast<uint4*>(&Bs[br * 40 + bh * 16]) =
            *reinterpret_cast<const uint4*>(wrowp + k0 + bh * 16);
        *reinterpret_cast<uint4*>(&Bs[br * 40 + bh * 16 + 8]) =
            *reinterpret_cast<const uint4*>(wrowp + k0 + bh * 16 + 8);
        __syncthreads();

        short8 af[4], bf[4];
#pragma unroll
        for (int fi = 0; fi < 4; ++fi)
            af[fi] = *reinterpret_cast<const short8*>(
                &As[(wrow * 64 + fi * 16 + (l & 15)) * 40 + ((l >> 4) << 3)]);
#pragma unroll
        for (int fj = 0; fj < 4; ++fj)
            bf[fj] = *reinterpret_cast<const short8*>(
                &Bs[(wcol * 64 + fj * 16 + (l & 15)) * 40 + ((l >> 4) << 3)]);
#pragma unroll
        for (int fi = 0; fi < 4; ++fi)
#pragma unroll
            for (int fj = 0; fj < 4; ++fj)
                acc[fi][fj] = __builtin_amdgcn_mfma_f32_16x16x32_bf16(
                    af[fi], bf[fj], acc[fi][fj], 0, 0, 0);
        __syncthreads();
    }

    float bias[4];
#pragma unroll
    for (int fj = 0; fj < 4; ++fj)
        bias[fj] = biasc[col0 + wcol * 64 + fj * 16 + (l & 15)];
#pragma unroll
    for (int fi = 0; fi < 4; ++fi)
#pragma unroll
        for (int fjp = 0; fjp < 2; ++fjp) {
            const int cg0 = col0 + wcol * 64 + fjp * 32;     // a=0,c=0 col
            const int g = cg0 >> 8;
            const int wv8 = (cg0 & 255) >> 5;
            const int word = g * 128 + wv8 * 16 + (l & 15);
#pragma unroll
            for (int q = 0; q < 4; ++q) {
                const int row = row0 + wrow * 64 + fi * 16 + ((l >> 4) << 2) + q;
                const int t = row & 63, n = row >> 6;
                const u32 lo = f2bf(acc[fi][2 * fjp][q] + bias[2 * fjp]);
                const u32 hi = f2bf(acc[fi][2 * fjp + 1][q] + bias[2 * fjp + 1]);
                xgw[((size_t)t * NROW + n) * 384 + word] = lo | (hi << 16);
            }
        }
}

// ---------------------------------------------------------------------------
// K2 (round-8/14 verbatim — empirical best, 114 µs): 64 blocks x 8 rows,
// 512 thr (8 waves, 2/EU). Weights ks0-5 AGPR-pinned, ks6-7 LDS. Lanes 0-31
// a=0, lanes 32-63 a=1 via shfl. xg prefetched one step ahead. One barrier.
// ---------------------------------------------------------------------------
__global__ __launch_bounds__(512)
__attribute__((amdgpu_waves_per_eu(2, 2)))
void k2_gru(const u32* __restrict__ xgw, const u16* __restrict__ whpk,
            const float* __restrict__ b_hh, float* __restrict__ mid)
{
    extern __shared__ u16 smem[];
    u16* wl = smem;                        // ks6-7: 48*2*64*8 u16 = 98304 B
    u16* hb = smem + 48 * 2 * 64 * 8;      // ping-pong 2 x 16*264 u16
    const int tid = threadIdx.x;
    const int l = tid & 63, wv = tid >> 6;   // wv in [0,8)
    const int n0 = blockIdx.x * 8;
    const int c = l & 15, rgrp = l >> 4;
    const int arow = c, klo = rgrp << 3;
    const int aSel = rgrp >> 1;              // 0: lanes 0-31, 1: lanes 32-63
    const int rbase = (rgrp & 1) * 4;        // rows rbase..rbase+3
    const int u = wv * 32 + aSel * 16 + c;   // hidden unit this lane updates

    // weights ks 0..5 (36 x short8 = 144 regs), pinned to AGPRs
    short8 wr[6][6];
#pragma unroll
    for (int gt = 0; gt < 3; ++gt)
#pragma unroll
        for (int a = 0; a < 2; ++a) {
            const int nt = gt * 16 + wv * 2 + a;
#pragma unroll
            for (int ks = 0; ks < 6; ++ks)
                wr[gt * 2 + a][ks] = *reinterpret_cast<const short8*>(
                    &whpk[(size_t)((nt * 8 + ks) * 64 + l) * 8]);
        }
    asm volatile("" :
        "+a"(wr[0][0]),"+a"(wr[0][1]),"+a"(wr[0][2]),"+a"(wr[0][3]),"+a"(wr[0][4]),"+a"(wr[0][5]),
        "+a"(wr[1][0]),"+a"(wr[1][1]),"+a"(wr[1][2]),"+a"(wr[1][3]),"+a"(wr[1][4]),"+a"(wr[1][5]),
        "+a"(wr[2][0]),"+a"(wr[2][1]),"+a"(wr[2][2]),"+a"(wr[2][3]),"+a"(wr[2][4]),"+a"(wr[2][5]));
    asm volatile("" :
        "+a"(wr[3][0]),"+a"(wr[3][1]),"+a"(wr[3][2]),"+a"(wr[3][3]),"+a"(wr[3][4]),"+a"(wr[3][5]),
        "+a"(wr[4][0]),"+a"(wr[4][1]),"+a"(wr[4][2]),"+a"(wr[4][3]),"+a"(wr[4][4]),"+a"(wr[4][5]),
        "+a"(wr[5][0]),"+a"(wr[5][1]),"+a"(wr[5][2]),"+a"(wr[5][3]),"+a"(wr[5][4]),"+a"(wr[5][5]));

    // stage ks 6..7 into LDS
    for (int cc = tid; cc < 48 * 2 * 64; cc += 512) {
        const int nt = cc >> 7, j = (cc >> 6) & 1, ll = cc & 63;
        *reinterpret_cast<uint4*>(&wl[(size_t)cc * 8]) =
            *reinterpret_cast<const uint4*>(
                &whpk[(size_t)((nt * 8 + 6 + j) * 64 + ll) * 8]);
    }
    for (int i = tid; i < 2 * 16 * 264 / 2; i += 512) ((u32*)hb)[i] = 0;

    const float bhn = b_hh[512 + u];
    u32 xo[4];
#pragma unroll
    for (int q = 0; q < 4; ++q)
        xo[q] = (u32)(n0 + rbase + q) * 384 + wv * 16 + c;
    float h[4] = {0.f, 0.f, 0.f, 0.f};
    const u32 stepw = (u32)NROW * 384;

    // prologue: load t=0 gates
    u32 xa[3][4], xn2[3][4];
#pragma unroll
    for (int q = 0; q < 4; ++q) {
        xa[0][q] = xgw[xo[q]];
        xa[1][q] = xgw[xo[q] + 128];
        xa[2][q] = xgw[xo[q] + 256];
    }

    __syncthreads();

    int p = 0;
    for (int t = 0; t < T_; ++t) {
        // prefetch next step's gates (fully hidden under this step)
        const u32 tb = (u32)(t + 1 < T_ ? t + 1 : T_ - 1) * stepw;
#pragma unroll
        for (int q = 0; q < 4; ++q) {
            xn2[0][q] = xgw[tb + xo[q]];
            xn2[1][q] = xgw[tb + xo[q] + 128];
            xn2[2][q] = xgw[tb + xo[q] + 256];
        }

        // MFMA phase: read hb[p]
        const u16* hbr = hb + p * (16 * 264);
        f32x4 acc[6];
#pragma unroll
        for (int m = 0; m < 6; ++m) acc[m] = (f32x4){0.f, 0.f, 0.f, 0.f};
        __builtin_amdgcn_s_setprio(1);
#pragma unroll
        for (int ks = 0; ks < 6; ++ks) {
            const short8 afr = *reinterpret_cast<const short8*>(
                &hbr[arow * 264 + ks * 32 + klo]);
#pragma unroll
            for (int m = 0; m < 6; ++m)
                acc[m] = __builtin_amdgcn_mfma_f32_16x16x32_bf16(
                    afr, wr[m][ks], acc[m], 0, 0, 0);
        }
#pragma unroll
        for (int ks = 6; ks < 8; ++ks) {
            const short8 afr = *reinterpret_cast<const short8*>(
                &hbr[arow * 264 + ks * 32 + klo]);
#pragma unroll
            for (int gt = 0; gt < 3; ++gt)
#pragma unroll
                for (int a = 0; a < 2; ++a) {
                    const int nt2 = (gt * 16 + wv * 2 + a) * 2 + (ks - 6);
                    const short8 bfr = *reinterpret_cast<const short8*>(
                        &wl[(size_t)(nt2 * 64 + l) * 8]);
                    acc[gt * 2 + a] = __builtin_amdgcn_mfma_f32_16x16x32_bf16(
                        afr, bfr, acc[gt * 2 + a], 0, 0, 0);
                }
        }
        __builtin_amdgcn_s_setprio(0);

        // redistribute: lanes>=32 take a=1 accs from lane l-32
        float vr[4], vz[4], vn[4];
#pragma unroll
        for (int q = 0; q < 4; ++q) {
            const float r1 = __shfl(acc[1][q], l & 31);
            const float z1 = __shfl(acc[3][q], l & 31);
            const float n1 = __shfl(acc[5][q], l & 31);
            vr[q] = (l < 32) ? acc[0][q] : r1;
            vz[q] = (l < 32) ? acc[2][q] : z1;
            vn[q] = (l < 32) ? acc[4][q] : n1;
        }

        // update phase: 4 (row,unit) values per lane, all 64 lanes active
        u16* hbw = hb + (p ^ 1) * (16 * 264);
#pragma unroll
        for (int q = 0; q < 4; ++q) {
            const float xr = aSel ? bf2f_hi(xa[0][q]) : bf2f_lo(xa[0][q]);
            const float xz = aSel ? bf2f_hi(xa[1][q]) : bf2f_lo(xa[1][q]);
            const float xn = aSel ? bf2f_hi(xa[2][q]) : bf2f_lo(xa[2][q]);
            const float rg = fsigm(xr + vr[q]);
            const float zg = fsigm(xz + vz[q]);
            const float ng = ftanh(xn + rg * (vn[q] + bhn));
            h[q] = zg * (h[q] - ng) + ng;
            hbw[(rbase + q) * 264 + u] = f2bf(h[q]);
        }

        // roll prefetch regs
#pragma unroll
        for (int g = 0; g < 3; ++g)
#pragma unroll
            for (int q = 0; q < 4; ++q) xa[g][q] = xn2[g][q];

        // single barrier per step
        asm volatile("s_waitcnt lgkmcnt(0)" ::: "memory");
        __builtin_amdgcn_sched_barrier(0);
        __builtin_amdgcn_s_barrier();
        __builtin_amdgcn_sched_barrier(0);
        p ^= 1;
    }

#pragma unroll
    for (int q = 0; q < 4; ++q)
        mid[(size_t)(n0 + rbase + q) * H_ + u] = h[q];
}

// ---------------------------------------------------------------------------
// K3: head. (unchanged)
// ---------------------------------------------------------------------------
__global__ __launch_bounds__(256) void k3_head(
    const float* __restrict__ mid,
    const u16* __restrict__ w2ft, const u16* __restrict__ w2bt,
    const float* __restrict__ b_ih2f, const float* __restrict__ b_hh2f,
    const float* __restrict__ b_ih2b, const float* __restrict__ b_hh2b,
    const u16* __restrict__ wc1t, const float* __restrict__ bc1,
    const float* __restrict__ wc2, const float* __restrict__ bc2,
    float* __restrict__ out)
{
    __shared__ float m[4][H_];
    __shared__ float xg2[2][4][G_];
    __shared__ float emb[4][512];
    __shared__ float hid[4][H_];
    int tid = threadIdx.x;
    int r0 = blockIdx.x * 4;

    for (int i = tid; i < 4 * H_; i += 256) {
        int r = i >> 8, k = i & 255;
        m[r][k] = mid[(size_t)(r0 + r) * H_ + k];
    }
    __syncthreads();

    const int g0 = tid, g1 = tid + 256, g2 = tid + 512;
    float bf0 = b_ih2f[g0] + b_hh2f[g0];
    float bf1 = b_ih2f[g1] + b_hh2f[g1];
    float bf2v = b_ih2f[g2];
    float bb0 = b_ih2b[g0] + b_hh2b[g0];
    float bb1 = b_ih2b[g1] + b_hh2b[g1];
    float bb2v = b_ih2b[g2];
    float af[4][3], ab[4][3];
#pragma unroll
    for (int r = 0; r < 4; ++r) {
        af[r][0] = bf0; af[r][1] = bf1; af[r][2] = bf2v;
        ab[r][0] = bb0; ab[r][1] = bb1; ab[r][2] = bb2v;
    }
#pragma unroll 4
    for (int k = 0; k < H_; ++k) {
        float wf0 = bf2f(w2ft[k * G_ + g0]);
        float wf1 = bf2f(w2ft[k * G_ + g1]);
        float wf2 = bf2f(w2ft[k * G_ + g2]);
        float wb0 = bf2f(w2bt[k * G_ + g0]);
        float wb1 = bf2f(w2bt[k * G_ + g1]);
        float wb2 = bf2f(w2bt[k * G_ + g2]);
#pragma unroll
        for (int r = 0; r < 4; ++r) {
            float mm = m[r][k];
            af[r][0] += mm * wf0; af[r][1] += mm * wf1; af[r][2] += mm * wf2;
            ab[r][0] += mm * wb0; ab[r][1] += mm * wb1; ab[r][2] += mm * wb2;
        }
    }
#pragma unroll
    for (int r = 0; r < 4; ++r) {
        xg2[0][r][g0] = af[r][0]; xg2[0][r][g1] = af[r][1]; xg2[0][r][g2] = af[r][2];
        xg2[1][r][g0] = ab[r][0]; xg2[1][r][g1] = ab[r][1]; xg2[1][r][g2] = ab[r][2];
    }
    __syncthreads();

    {
        const int j = tid;
        float bnf = b_hh2f[512 + j], bnb = b_hh2b[512 + j];
#pragma unroll
        for (int r = 0; r < 4; ++r) {
            float rg = sigm(xg2[0][r][j]);
            float zg = sigm(xg2[0][r][256 + j]);
            float ng = tanhf(xg2[0][r][512 + j] + rg * bnf);
            emb[r][j] = (1.f - zg) * ng;
            rg = sigm(xg2[1][r][j]);
            zg = sigm(xg2[1][r][256 + j]);
            ng = tanhf(xg2[1][r][512 + j] + rg * bnb);
            emb[r][256 + j] = (1.f - zg) * ng;
        }
    }
    __syncthreads();

    {
        const int o = tid;
        float acc[4];
        float b = bc1[o];
#pragma unroll
        for (int r = 0; r < 4; ++r) acc[r] = b;
#pragma unroll 4
        for (int k = 0; k < 512; ++k) {
            float w = bf2f(wc1t[k * H_ + o]);
#pragma unroll
            for (int r = 0; r < 4; ++r) acc[r] += emb[r][k] * w;
        }
#pragma unroll
        for (int r = 0; r < 4; ++r) {
            float pre = acc[r];
            hid[r][o] = pre >= 0.f ? pre : 0.1f * pre;
        }
    }
    __syncthreads();

    {
        int grp = tid >> 5, lane = tid & 31;
        int r = grp >> 1, cc = grp & 1;
        float s = 0.f;
        for (int k = lane; k < H_; k += 32) s += hid[r][k] * wc2[cc * H_ + k];
#pragma unroll
        for (int msk = 16; msk >= 1; msk >>= 1) s += __shfl_xor(s, msk, 32);
        if (lane == 0) out[(size_t)(r0 + r) * 2 + cc] = s + bc2[cc];
    }
}

// ---------------------------------------------------------------------------
extern "C" void kernel_launch(void* const* d_in, const int* in_sizes, int n_in,
                              void* d_out, int out_size, void* d_ws, size_t ws_size,
                              hipStream_t stream)
{
    const float* x      = (const float*)d_in[0];
    const float* w_ih1  = (const float*)d_in[1];
    const float* w_hh1  = (const float*)d_in[2];
    const float* b_ih1  = (const float*)d_in[3];
    const float* b_hh1  = (const float*)d_in[4];
    const float* w_ih2f = (const float*)d_in[5];
    const float* b_ih2f = (const float*)d_in[7];
    const float* b_hh2f = (const float*)d_in[8];
    const float* w_ih2b = (const float*)d_in[9];
    const float* b_ih2b = (const float*)d_in[11];
    const float* b_hh2b = (const float*)d_in[12];
    const float* wc1    = (const float*)d_in[13];
    const float* bc1    = (const float*)d_in[14];
    const float* wc2    = (const float*)d_in[15];
    const float* bc2    = (const float*)d_in[16];
    float* out = (float*)d_out;

    char* p = (char*)d_ws;
    u32* xgw  = (u32*)p;  p += (size_t)M_ * 384 * 4;         // 48 MB [t][n][3][128]u32
    u16* wihb = (u16*)p;  p += (size_t)G_ * KP_ * 2;         // 480 KB
    u16* whpk = (u16*)p;  p += (size_t)48 * 8 * 64 * 8 * 2;  // 384 KB
    u16* w2ft = (u16*)p;  p += (size_t)G_ * H_ * 2;
    u16* w2bt = (u16*)p;  p += (size_t)G_ * H_ * 2;
    u16* wc1t = (u16*)p;  p += (size_t)512 * 256 * 2;
    float* mid = (float*)p; p += (size_t)NROW * H_ * 4;
    float* biasc = (float*)p; p += (size_t)G_ * 4;

    k0_prep<<<dim3(960, 5), 256, 0, stream>>>(w_ih1, w_hh1, b_ih1, b_hh1,
                                              w_ih2f, w_ih2b, wc1,
                                              wihb, whpk, w2ft, w2bt, wc1t, biasc);
    k1_xgemm<<<dim3(M_ / 128, 3), 512, 0, stream>>>(x, wihb, biasc, xgw);
    const int k2_lds = (48 * 2 * 64 * 8 + 2 * 16 * 264) * 2;   // 115200 B
    k2_gru<<<64, 512, k2_lds, stream>>>(xgw, whpk, b_hh1, mid);
    k3_head<<<128, 256, 0, stream>>>(mid, w2ft, w2bt, b_ih2f, b_hh2f,
                                     b_ih2b, b_hh2b, wc1t, bc1, wc2, bc2, out);
}